// Round 5
// baseline (2288.447 us; speedup 1.0000x reference)
//
#include <hip/hip_runtime.h>
#include <hip/hip_bf16.h>
#include <cstdint>

#define NN 50000
#define NE 800000

typedef _Float16 f16;
typedef f16 f16x8 __attribute__((ext_vector_type(8)));
typedef f16 f16x4 __attribute__((ext_vector_type(4)));
typedef float f32x4 __attribute__((ext_vector_type(4)));

#define TB_STR 136   // f16 stride for [64][128] intermediate (272B)

// ============================================================================
// Weight pre-pack (f16 MFMA fragment layout; A/B frag layouts symmetric).
// unit = kc*8 + ct ; element [lane][i] = W[kc*32 + (lane>>4)*8 + i][ct*16 + (lane&15)]
// Edge pack per layer: et_w1 72 units | et_w2 32 | msg_w1 32 | msg_w2 32 = 168
// ============================================================================
__global__ void pack_w_kernel(const float* __restrict__ et_w1,
                              const float* __restrict__ et_w2,
                              const float* __restrict__ msg_w1,
                              const float* __restrict__ msg_w2,
                              f16* __restrict__ wpack) {
  int idx = blockIdx.x * 256 + threadIdx.x;
  if (idx >= 4 * 86016) return;
  int l = idx / 86016;
  int rem = idx - l * 86016;
  int unit = rem >> 9;
  int e = rem & 511;
  int ln = e >> 3, i = e & 7;
  const float* src;
  int ul;
  if (unit < 72)       { src = et_w1  + (size_t)l * 288 * 128; ul = unit; }
  else if (unit < 104) { src = et_w2  + (size_t)l * 128 * 128; ul = unit - 72; }
  else if (unit < 136) { src = msg_w1 + (size_t)l * 128 * 128; ul = unit - 104; }
  else                 { src = msg_w2 + (size_t)l * 128 * 128; ul = unit - 136; }
  int kc = ul >> 3, ct = ul & 7;
  int k = kc * 32 + (ln >> 4) * 8 + i;
  int col = ct * 16 + (ln & 15);
  wpack[idx] = (f16)src[k * 128 + col];
}

// Update pack per layer: upd_w1 (K=256) 64 units | upd_w2 32 units = 96
__global__ void pack_upd_kernel(const float* __restrict__ upd_w1,
                                const float* __restrict__ upd_w2,
                                f16* __restrict__ wpu) {
  int idx = blockIdx.x * 256 + threadIdx.x;
  if (idx >= 4 * 96 * 512) return;
  int l = idx / (96 * 512);
  int rem = idx - l * (96 * 512);
  int unit = rem >> 9, e = rem & 511, ln = e >> 3, i = e & 7;
  const float* src;
  int ul;
  if (unit < 64) { src = upd_w1 + (size_t)l * 256 * 128; ul = unit; }
  else           { src = upd_w2 + (size_t)l * 128 * 128; ul = unit - 64; }
  int kc = ul >> 3, ct = ul & 7;
  int k = kc * 32 + (ln >> 4) * 8 + i;
  int col = ct * 16 + (ln & 15);
  wpu[idx] = (f16)src[k * 128 + col];
}

// edge_attr -> f16 (once; saves 51MB fetch + cvt per edge dispatch)
__global__ void cvt_ea_kernel(const float* __restrict__ ea, f16* __restrict__ ea16) {
  int idx = blockIdx.x * 256 + threadIdx.x;   // over NE*32/8 f16x8 chunks
  if (idx >= NE * 4) return;
  const float* sp = ea + (size_t)idx * 8;
  float4 u0 = *(const float4*)sp, u1 = *(const float4*)(sp + 4);
  f16x8 v = {(f16)u0.x, (f16)u0.y, (f16)u0.z, (f16)u0.w,
             (f16)u1.x, (f16)u1.y, (f16)u1.z, (f16)u1.w};
  *(f16x8*)(ea16 + (size_t)idx * 8) = v;
}

// ============================================================================
// Edge kernel: D-normal orientation. Wave (wr,wc): rows wr*32..+32,
// cols wc*64..+64. acc[rt][ct], rt=row 16-tile, ct=col 16-tile.
// A-frag: lane(cl,kh) -> row +cl, k=kc*32+kh*8..+8.
// C/D: lane holds col=ct*16+cl, rows rt*16+kh*4+{0..3}  (m89-verified).
// Single LDS intermediate buffer; compute->barrier->store-in-place->barrier.
// ============================================================================
#define EDGE_ACC_INIT(BIAS)                                                    \
  _Pragma("unroll") for (int ct = 0; ct < 4; ++ct) {                           \
    float bv_ = (BIAS)[wc * 64 + ct * 16 + cl];                                \
    acc[0][ct] = (f32x4){bv_, bv_, bv_, bv_};                                  \
    acc[1][ct] = acc[0][ct];                                                   \
  }

#define EDGE_MFMA_KC(A0, A1, UNIT)                                             \
  _Pragma("unroll") for (int ct = 0; ct < 4; ++ct) {                           \
    f16x8 b_ = *(const f16x8*)&wp[(size_t)(((UNIT) + wc * 4 + ct) * 64 + lane) * 8]; \
    acc[0][ct] = __builtin_amdgcn_mfma_f32_16x16x32_f16(A0, b_, acc[0][ct], 0, 0, 0); \
    acc[1][ct] = __builtin_amdgcn_mfma_f32_16x16x32_f16(A1, b_, acc[1][ct], 0, 0, 0); \
  }

// GEMM with A from LDS (stride TB_STR), K=128
#define EDGE_GEMM_LDS(APTR, UNIT0, BIAS)                                       \
  {                                                                            \
    EDGE_ACC_INIT(BIAS);                                                       \
    _Pragma("unroll") for (int kc = 0; kc < 4; ++kc) {                         \
      f16x8 a0_ = *(const f16x8*)&(APTR)[(wr * 32 + cl) * TB_STR + kc * 32 + kh * 8]; \
      f16x8 a1_ = *(const f16x8*)&(APTR)[(wr * 32 + 16 + cl) * TB_STR + kc * 32 + kh * 8]; \
      EDGE_MFMA_KC(a0_, a1_, (UNIT0) + kc * 8);                                \
    }                                                                          \
  }

#define EDGE_STORE(DST, RELU)                                                  \
  _Pragma("unroll") for (int rt = 0; rt < 2; ++rt)                             \
    _Pragma("unroll") for (int ct = 0; ct < 4; ++ct)                           \
      _Pragma("unroll") for (int i = 0; i < 4; ++i) {                          \
        float v_ = acc[rt][ct][i];                                             \
        if (RELU) v_ = fmaxf(v_, 0.f);                                         \
        (DST)[(wr * 32 + rt * 16 + kh * 4 + i) * TB_STR + wc * 64 + ct * 16 + cl] = (f16)v_; \
      }

__global__ __launch_bounds__(256, 8)
void edge_mfma_kernel(const f16* __restrict__ h16, const f16* __restrict__ ea16,
                      const int* __restrict__ esrc, const int* __restrict__ edst,
                      const f16* __restrict__ wp,
                      const float* __restrict__ b1, const float* __restrict__ b2,
                      const float* __restrict__ b3, const float* __restrict__ b4,
                      float* __restrict__ aggr) {
  __shared__ f16 buf[64 * TB_STR];
  __shared__ int eidx[128];       // [0:64) dst, [64:128) src
  const int tid = threadIdx.x;
  const int lane = tid & 63;
  const int wv = tid >> 6;
  const int wr = wv >> 1, wc = wv & 1;
  const int cl = lane & 15;
  const int kh = lane >> 4;
  const int e0 = blockIdx.x * 64;
  if (tid < 64) eidx[tid] = edst[e0 + tid];
  else if (tid < 128) eidx[tid] = esrc[e0 + tid - 64];
  __syncthreads();

  const int r0 = wr * 32 + cl, r1 = r0 + 16;
  const f16* pd0 = h16 + (size_t)eidx[r0] * 128 + kh * 8;       // x_i = h[dst]
  const f16* pd1 = h16 + (size_t)eidx[r1] * 128 + kh * 8;
  const f16* ps0 = h16 + (size_t)eidx[64 + r0] * 128 + kh * 8;  // x_j = h[src]
  const f16* ps1 = h16 + (size_t)eidx[64 + r1] * 128 + kh * 8;
  const f16* pe0 = ea16 + (size_t)(e0 + r0) * 32 + kh * 8;
  const f16* pe1 = ea16 + (size_t)(e0 + r1) * 32 + kh * 8;

  f32x4 acc[2][4];
  // ---- GEMM1: et hidden, K=288, A direct from global ----
  EDGE_ACC_INIT(b1);
#pragma unroll
  for (int kc = 0; kc < 4; ++kc) {                  // k in [0,128): h[dst]
    f16x8 a0_ = *(const f16x8*)(pd0 + kc * 32);
    f16x8 a1_ = *(const f16x8*)(pd1 + kc * 32);
    EDGE_MFMA_KC(a0_, a1_, kc * 8);
  }
#pragma unroll
  for (int kc = 4; kc < 8; ++kc) {                  // k in [128,256): h[src]
    f16x8 a0_ = *(const f16x8*)(ps0 + (kc - 4) * 32);
    f16x8 a1_ = *(const f16x8*)(ps1 + (kc - 4) * 32);
    EDGE_MFMA_KC(a0_, a1_, kc * 8);
  }
  {                                                  // k in [256,288): ea16
    f16x8 a0_ = *(const f16x8*)pe0;
    f16x8 a1_ = *(const f16x8*)pe1;
    EDGE_MFMA_KC(a0_, a1_, 64);
  }
  EDGE_STORE(buf, 1);
  __syncthreads();
  // ---- GEMM2: e_emb, K=128 ----
  EDGE_GEMM_LDS(buf, 72, b2);
  __syncthreads();                 // all reads of buf complete
  EDGE_STORE(buf, 0);
  __syncthreads();
  // ---- GEMM3: msg hidden, K=128 ----
  EDGE_GEMM_LDS(buf, 104, b3);
  __syncthreads();
  EDGE_STORE(buf, 1);
  __syncthreads();
  // ---- GEMM4: msg, K=128 -> atomic scatter (sector-contiguous pattern) ----
  EDGE_GEMM_LDS(buf, 136, b4);
#pragma unroll
  for (int rt = 0; rt < 2; ++rt) {
#pragma unroll
    for (int i = 0; i < 4; ++i) {
      int row = wr * 32 + rt * 16 + kh * 4 + i;
      float* ap = aggr + (size_t)eidx[row] * 128 + wc * 64 + cl;
#pragma unroll
      for (int ct = 0; ct < 4; ++ct)
        unsafeAtomicAdd(ap + ct * 16, acc[rt][ct][i]);
    }
  }
}

// ============================================================================
// Transposed-D MFMA machinery (update kernel; no atomics there)
// ============================================================================
#define MFMA_T(APTR, ASTR, ASWZ, NKC, UNIT0, BIAS)                             \
  {                                                                            \
    _Pragma("unroll") for (int nt = 0; nt < 2; ++nt) {                         \
      f32x4 bv_ = *(const f32x4*)((BIAS) + wv * 32 + nt * 16 + kh * 4);        \
      _Pragma("unroll") for (int et = 0; et < 4; ++et) acc[nt][et] = bv_;      \
    }                                                                          \
    _Pragma("unroll 2") for (int kc = 0; kc < (NKC); ++kc) {                   \
      f16x8 wfr_[2];                                                           \
      _Pragma("unroll") for (int nt = 0; nt < 2; ++nt)                         \
        wfr_[nt] = *(const f16x8*)&wp[(size_t)(((UNIT0) + kc * 8 + wv * 2 + nt) * 64 + lane) * 8]; \
      _Pragma("unroll") for (int et = 0; et < 4; ++et) {                       \
        int r_ = et * 16 + cl;                                                 \
        int idx_ = r_ * (ASTR) + kc * 32 + kh * 8;                             \
        if (ASWZ) idx_ ^= ((r_ & 7) << 3);                                     \
        f16x8 efr_ = *(const f16x8*)&(APTR)[idx_];                             \
        _Pragma("unroll") for (int nt = 0; nt < 2; ++nt)                       \
          acc[nt][et] = __builtin_amdgcn_mfma_f32_16x16x32_f16(wfr_[nt], efr_, acc[nt][et], 0, 0, 0); \
      }                                                                        \
    }                                                                          \
  }

#define STORE_T(DPTR, RELU)                                                    \
  _Pragma("unroll") for (int nt = 0; nt < 2; ++nt)                             \
    _Pragma("unroll") for (int et = 0; et < 4; ++et) {                         \
      float v0_ = acc[nt][et][0], v1_ = acc[nt][et][1],                        \
            v2_ = acc[nt][et][2], v3_ = acc[nt][et][3];                        \
      if (RELU) { v0_ = fmaxf(v0_, 0.f); v1_ = fmaxf(v1_, 0.f);                \
                  v2_ = fmaxf(v2_, 0.f); v3_ = fmaxf(v3_, 0.f); }              \
      int r_ = et * 16 + cl;                                                   \
      int idx_ = (r_ * 128 + wv * 32 + nt * 16 + kh * 4) ^ ((r_ & 7) << 3);    \
      *(f16x4*)&(DPTR)[idx_] = (f16x4){(f16)v0_, (f16)v1_, (f16)v2_, (f16)v3_};\
    }

// ============================================================================
// update: h' = LN(h + MLP2([h|aggr]))  -- f16 MFMA, writes h16
// ============================================================================
__global__ __launch_bounds__(256, 2)
void update_mfma_kernel(const f16* __restrict__ h16, const float* __restrict__ aggr,
                        const f16* __restrict__ wp,
                        const float* __restrict__ b1, const float* __restrict__ b2,
                        const float* __restrict__ lng, const float* __restrict__ lnb,
                        f16* __restrict__ h16out) {
  __shared__ f16 ua[64 * 264];
  __shared__ f16 tb[64 * 128];
  __shared__ f16 emb[64 * 128];
  const int tid = threadIdx.x;
  const int lane = tid & 63;
  const int wv = tid >> 6;
  const int cl = lane & 15;
  const int kh = lane >> 4;
  const int r0 = blockIdx.x * 64;
#pragma unroll
  for (int it = 0; it < 8; ++it) {
    int f = tid + it * 256;
    int row = f >> 5, c8 = f & 31;
    int grow = r0 + row;
    f16x8 v = {};
    if (grow < NN) {
      if (c8 < 16) {
        v = *(const f16x8*)(h16 + (size_t)grow * 128 + c8 * 8);
      } else {
        const float* sp = aggr + (size_t)grow * 128 + (c8 - 16) * 8;
        float4 u0 = *(const float4*)sp, u1 = *(const float4*)(sp + 4);
        v = (f16x8){(f16)u0.x, (f16)u0.y, (f16)u0.z, (f16)u0.w,
                    (f16)u1.x, (f16)u1.y, (f16)u1.z, (f16)u1.w};
      }
    }
    *(f16x8*)&ua[row * 264 + c8 * 8] = v;
  }
  __syncthreads();
  f32x4 acc[2][4];
  MFMA_T(ua, 264, 0, 8, 0, b1);             // upd hidden, K=256
  STORE_T(tb, 1);
  __syncthreads();
  MFMA_T(tb, 128, 1, 4, 64, b2);            // h_new, K=128
  STORE_T(emb, 0);
  __syncthreads();
  {
    const int row = tid >> 2, q = tid & 3;
    const int grow = r0 + row;
    float y[32];
    float s = 0.f, ss = 0.f;
#pragma unroll
    for (int j = 0; j < 4; ++j) {
      int col = q * 32 + j * 8;
      int ei = (row * 128 + col) ^ ((row & 7) << 3);
      f16x8 ev = *(const f16x8*)&emb[ei];
      f16x8 rv = *(const f16x8*)&ua[row * 264 + col];
#pragma unroll
      for (int e = 0; e < 8; ++e) {
        float t = (float)ev[e] + (float)rv[e];
        y[j * 8 + e] = t; s += t; ss += t * t;
      }
    }
    s += __shfl_xor(s, 1);  s += __shfl_xor(s, 2);
    ss += __shfl_xor(ss, 1); ss += __shfl_xor(ss, 2);
    float mean = s * (1.f / 128.f);
    float var = ss * (1.f / 128.f) - mean * mean;
    float rstd = rsqrtf(var + 1e-5f);
    if (grow < NN) {
#pragma unroll
      for (int j = 0; j < 4; ++j) {
        int col = q * 32 + j * 8;
        const float4 g0 = *(const float4*)(lng + col), g1 = *(const float4*)(lng + col + 4);
        const float4 q0 = *(const float4*)(lnb + col), q1 = *(const float4*)(lnb + col + 4);
        float gv[8] = {g0.x, g0.y, g0.z, g0.w, g1.x, g1.y, g1.z, g1.w};
        float bv[8] = {q0.x, q0.y, q0.z, q0.w, q1.x, q1.y, q1.z, q1.w};
        f16x8 o;
#pragma unroll
        for (int e = 0; e < 8; ++e)
          o[e] = (f16)((y[j * 8 + e] - mean) * rstd * gv[e] + bv[e]);
        *(f16x8*)(h16out + (size_t)grow * 128 + col) = o;
      }
    }
  }
}

// ============================================================================
// fp32 register-tiled machinery (encoder only)
// ============================================================================
#define ACC_INIT(BPTR)                                                        \
  {                                                                           \
    const float4 bA_ = *(const float4*)((BPTR) + cg * 8);                     \
    const float4 bB_ = *(const float4*)((BPTR) + cg * 8 + 4);                 \
    _Pragma("unroll") for (int i_ = 0; i_ < 4; ++i_) {                        \
      acc[i_][0] = bA_.x; acc[i_][1] = bA_.y; acc[i_][2] = bA_.z;             \
      acc[i_][3] = bA_.w; acc[i_][4] = bB_.x; acc[i_][5] = bB_.y;             \
      acc[i_][6] = bB_.z; acc[i_][7] = bB_.w;                                 \
    }                                                                         \
  }

#define GEMM_STEP(ABUF, ASTR, WPTR)                                           \
  {                                                                           \
    const float4 w0_ = *(const float4*)((WPTR) + (size_t)k * 128 + cg * 8);   \
    const float4 w1_ = *(const float4*)((WPTR) + (size_t)k * 128 + cg * 8 + 4);\
    float wv_[8] = {w0_.x, w0_.y, w0_.z, w0_.w, w1_.x, w1_.y, w1_.z, w1_.w};  \
    float av_[4];                                                             \
    _Pragma("unroll") for (int i_ = 0; i_ < 4; ++i_)                          \
        av_[i_] = (ABUF)[(rg * 4 + i_) * (ASTR) + k];                         \
    _Pragma("unroll") for (int i_ = 0; i_ < 4; ++i_)                          \
      _Pragma("unroll") for (int j_ = 0; j_ < 8; ++j_)                        \
          acc[i_][j_] = fmaf(av_[i_], wv_[j_], acc[i_][j_]);                  \
  }

#define STORE_LDS_RELU(TBUF, TSTR)                                            \
  _Pragma("unroll") for (int i_ = 0; i_ < 4; ++i_) {                          \
    *(float4*)&(TBUF)[(rg * 4 + i_) * (TSTR) + cg * 8] =                      \
        make_float4(fmaxf(acc[i_][0], 0.f), fmaxf(acc[i_][1], 0.f),           \
                    fmaxf(acc[i_][2], 0.f), fmaxf(acc[i_][3], 0.f));          \
    *(float4*)&(TBUF)[(rg * 4 + i_) * (TSTR) + cg * 8 + 4] =                  \
        make_float4(fmaxf(acc[i_][4], 0.f), fmaxf(acc[i_][5], 0.f),           \
                    fmaxf(acc[i_][6], 0.f), fmaxf(acc[i_][7], 0.f));          \
  }

__global__ void gru_transpose_kernel(const float* __restrict__ wih,
                                     const float* __restrict__ whh,
                                     float* __restrict__ wihT,
                                     float* __restrict__ whhT) {
  int idx = blockIdx.x * 256 + threadIdx.x;
  if (idx < 128 * 384) {
    int k = idx / 384;
    int j = idx - k * 384;
    wihT[idx] = wih[j * 128 + k];
    whhT[idx] = whh[j * 128 + k];
  }
}

__global__ __launch_bounds__(256, 2)
void encoder_kernel(const float* __restrict__ x,
                    const float* __restrict__ w1, const float* __restrict__ b1,
                    const float* __restrict__ w2, const float* __restrict__ b2,
                    f16* __restrict__ h16out) {
  __shared__ float xa[64 * 132];
  __shared__ float tb[64 * 132];
  const int tid = threadIdx.x;
  const int cg = tid & 15, rg = tid >> 4;
  const int r0 = blockIdx.x * 64;
#pragma unroll
  for (int it = 0; it < 8; ++it) {
    int f = tid + it * 256;
    int row = f >> 5, c4 = f & 31;
    float4 v = make_float4(0.f, 0.f, 0.f, 0.f);
    int grow = r0 + row;
    if (grow < NN) v = *(const float4*)(x + (size_t)grow * 128 + c4 * 4);
    *(float4*)&xa[row * 132 + c4 * 4] = v;
  }
  __syncthreads();
  float acc[4][8];
  ACC_INIT(b1);
#pragma unroll 2
  for (int k = 0; k < 128; ++k) GEMM_STEP(xa, 132, w1);
  STORE_LDS_RELU(tb, 132);
  __syncthreads();
  ACC_INIT(b2);
#pragma unroll 2
  for (int k = 0; k < 128; ++k) GEMM_STEP(tb, 132, w2);
#pragma unroll
  for (int i = 0; i < 4; ++i) {
    int grow = r0 + rg * 4 + i;
    if (grow < NN) {
      f16x8 o = {(f16)acc[i][0], (f16)acc[i][1], (f16)acc[i][2], (f16)acc[i][3],
                 (f16)acc[i][4], (f16)acc[i][5], (f16)acc[i][6], (f16)acc[i][7]};
      *(f16x8*)(h16out + (size_t)grow * 128 + cg * 8) = o;
    }
  }
}

__global__ __launch_bounds__(256, 4)
void gru_kernel(const f16* __restrict__ h16, const float* __restrict__ hprev,
                const float* __restrict__ wihT, const float* __restrict__ whhT,
                const float* __restrict__ bih, const float* __restrict__ bhh,
                float* __restrict__ out) {
  __shared__ float ha[32 * 132];
  __shared__ float hp[32 * 132];
  const int tid = threadIdx.x, cg = tid & 15, rg = tid >> 4;
  const int r0 = blockIdx.x * 32;
#pragma unroll
  for (int it = 0; it < 2; ++it) {
    int f = tid + it * 256;
    int row = f >> 4, c8 = f & 15;
    int grow = r0 + row;
    f16x8 v = {};
    if (grow < NN) v = *(const f16x8*)(h16 + (size_t)grow * 128 + c8 * 8);
    float* dp = &ha[row * 132 + c8 * 8];
    *(float4*)dp = make_float4((float)v[0], (float)v[1], (float)v[2], (float)v[3]);
    *(float4*)(dp + 4) = make_float4((float)v[4], (float)v[5], (float)v[6], (float)v[7]);
  }
#pragma unroll
  for (int it = 0; it < 4; ++it) {
    int f = tid + it * 256;
    int row = f >> 5, c4 = f & 31;
    int grow = r0 + row;
    float4 vp = make_float4(0.f, 0.f, 0.f, 0.f);
    if (grow < NN) vp = *(const float4*)(hprev + (size_t)grow * 128 + c4 * 4);
    *(float4*)&hp[row * 132 + c4 * 4] = vp;
  }
  __syncthreads();
  float rgate[2][8], zgate[2][8];
#pragma unroll
  for (int c = 0; c < 2; ++c) {
    float acc[2][8];
#pragma unroll
    for (int j = 0; j < 8; ++j) {
      float bsum = bih[c * 128 + cg * 8 + j] + bhh[c * 128 + cg * 8 + j];
      acc[0][j] = bsum; acc[1][j] = bsum;
    }
    for (int k = 0; k < 128; ++k) {
      const float* wi = wihT + (size_t)k * 384 + c * 128 + cg * 8;
      const float* wh = whhT + (size_t)k * 384 + c * 128 + cg * 8;
      const float4 wi0 = *(const float4*)wi, wi1 = *(const float4*)(wi + 4);
      const float4 wh0 = *(const float4*)wh, wh1 = *(const float4*)(wh + 4);
      float wiv[8] = {wi0.x, wi0.y, wi0.z, wi0.w, wi1.x, wi1.y, wi1.z, wi1.w};
      float whv[8] = {wh0.x, wh0.y, wh0.z, wh0.w, wh1.x, wh1.y, wh1.z, wh1.w};
      float a0 = ha[(rg * 2 + 0) * 132 + k], a1 = ha[(rg * 2 + 1) * 132 + k];
      float p0 = hp[(rg * 2 + 0) * 132 + k], p1 = hp[(rg * 2 + 1) * 132 + k];
#pragma unroll
      for (int j = 0; j < 8; ++j) {
        acc[0][j] = fmaf(a0, wiv[j], acc[0][j]);
        acc[1][j] = fmaf(a1, wiv[j], acc[1][j]);
        acc[0][j] = fmaf(p0, whv[j], acc[0][j]);
        acc[1][j] = fmaf(p1, whv[j], acc[1][j]);
      }
    }
#pragma unroll
    for (int i = 0; i < 2; ++i)
#pragma unroll
      for (int j = 0; j < 8; ++j) {
        float sg = 1.f / (1.f + __expf(-acc[i][j]));
        if (c == 0) rgate[i][j] = sg; else zgate[i][j] = sg;
      }
  }
  float ai[2][8], ah[2][8];
#pragma unroll
  for (int j = 0; j < 8; ++j) {
    float bi = bih[256 + cg * 8 + j], bh = bhh[256 + cg * 8 + j];
    ai[0][j] = bi; ai[1][j] = bi;
    ah[0][j] = bh; ah[1][j] = bh;
  }
  for (int k = 0; k < 128; ++k) {
    const float* wi = wihT + (size_t)k * 384 + 256 + cg * 8;
    const float* wh = whhT + (size_t)k * 384 + 256 + cg * 8;
    const float4 wi0 = *(const float4*)wi, wi1 = *(const float4*)(wi + 4);
    const float4 wh0 = *(const float4*)wh, wh1 = *(const float4*)(wh + 4);
    float wiv[8] = {wi0.x, wi0.y, wi0.z, wi0.w, wi1.x, wi1.y, wi1.z, wi1.w};
    float whv[8] = {wh0.x, wh0.y, wh0.z, wh0.w, wh1.x, wh1.y, wh1.z, wh1.w};
    float a0 = ha[(rg * 2 + 0) * 132 + k], a1 = ha[(rg * 2 + 1) * 132 + k];
    float p0 = hp[(rg * 2 + 0) * 132 + k], p1 = hp[(rg * 2 + 1) * 132 + k];
#pragma unroll
    for (int j = 0; j < 8; ++j) {
      ai[0][j] = fmaf(a0, wiv[j], ai[0][j]);
      ai[1][j] = fmaf(a1, wiv[j], ai[1][j]);
      ah[0][j] = fmaf(p0, whv[j], ah[0][j]);
      ah[1][j] = fmaf(p1, whv[j], ah[1][j]);
    }
  }
#pragma unroll
  for (int i = 0; i < 2; ++i) {
    int grow = r0 + rg * 2 + i;
    if (grow >= NN) continue;
    float o[8];
#pragma unroll
    for (int j = 0; j < 8; ++j) {
      float nn_ = tanhf(fmaf(rgate[i][j], ah[i][j], ai[i][j]));
      float hpv = hp[(rg * 2 + i) * 132 + cg * 8 + j];
      o[j] = (1.f - zgate[i][j]) * nn_ + zgate[i][j] * hpv;
    }
    *(float4*)(out + (size_t)grow * 128 + cg * 8) = make_float4(o[0], o[1], o[2], o[3]);
    *(float4*)(out + (size_t)grow * 128 + cg * 8 + 4) = make_float4(o[4], o[5], o[6], o[7]);
  }
}

// ---------------- launch ----------------
extern "C" void kernel_launch(void* const* d_in, const int* in_sizes, int n_in,
                              void* d_out, int out_size, void* d_ws, size_t ws_size,
                              hipStream_t stream) {
  (void)in_sizes; (void)n_in; (void)out_size; (void)ws_size;
  const float* x         = (const float*)d_in[0];
  const float* edge_attr = (const float*)d_in[1];
  const float* h_prev    = (const float*)d_in[2];
  const float* enc_w1    = (const float*)d_in[3];
  const float* enc_b1    = (const float*)d_in[4];
  const float* enc_w2    = (const float*)d_in[5];
  const float* enc_b2    = (const float*)d_in[6];
  const float* et_w1     = (const float*)d_in[7];
  const float* et_b1     = (const float*)d_in[8];
  const float* et_w2     = (const float*)d_in[9];
  const float* et_b2     = (const float*)d_in[10];
  const float* msg_w1    = (const float*)d_in[11];
  const float* msg_b1    = (const float*)d_in[12];
  const float* msg_w2    = (const float*)d_in[13];
  const float* msg_b2    = (const float*)d_in[14];
  const float* upd_w1    = (const float*)d_in[15];
  const float* upd_b1    = (const float*)d_in[16];
  const float* upd_w2    = (const float*)d_in[17];
  const float* upd_b2    = (const float*)d_in[18];
  const float* ln_g      = (const float*)d_in[19];
  const float* ln_b      = (const float*)d_in[20];
  const float* gru_wih   = (const float*)d_in[21];
  const float* gru_whh   = (const float*)d_in[22];
  const float* gru_bih   = (const float*)d_in[23];
  const float* gru_bhh   = (const float*)d_in[24];
  const int* edge_index  = (const int*)d_in[25];
  const int* esrc = edge_index;        // edge_index[0]
  const int* edst = edge_index + NE;   // edge_index[1]

  float* ws   = (float*)d_ws;
  float* aggr = ws;                                  // N*128 f32
  float* wihT = ws + (size_t)NN * 128;               // 128*384
  float* whhT = wihT + 128 * 384;                    // 128*384
  f16*   h16a = (f16*)(whhT + 128 * 384);            // N*128 f16
  f16*   h16b = h16a + (size_t)NN * 128;             // N*128 f16
  f16*   wpe  = h16b + (size_t)NN * 128;             // 4*168*512 f16
  f16*   wpu  = wpe + 4 * 86016;                     // 4*96*512 f16
  f16*   ea16 = wpu + 4 * 96 * 512;                  // E*32 f16

  gru_transpose_kernel<<<192, 256, 0, stream>>>(gru_wih, gru_whh, wihT, whhT);
  pack_w_kernel<<<(4 * 86016 + 255) / 256, 256, 0, stream>>>(et_w1, et_w2, msg_w1, msg_w2, wpe);
  pack_upd_kernel<<<(4 * 96 * 512 + 255) / 256, 256, 0, stream>>>(upd_w1, upd_w2, wpu);
  cvt_ea_kernel<<<(NE * 4 + 255) / 256, 256, 0, stream>>>(edge_attr, ea16);
  encoder_kernel<<<(NN + 63) / 64, 256, 0, stream>>>(x, enc_w1, enc_b1, enc_w2, enc_b2, h16a);

  f16* hc = h16a;
  f16* hn = h16b;
  for (int l = 0; l < 4; ++l) {
    hipMemsetAsync(aggr, 0, (size_t)NN * 128 * sizeof(float), stream);
    edge_mfma_kernel<<<NE / 64, 256, 0, stream>>>(
        hc, ea16, esrc, edst,
        wpe + (size_t)l * 86016,
        et_b1 + l * 128, et_b2 + l * 128,
        msg_b1 + l * 128, msg_b2 + l * 128,
        aggr);
    update_mfma_kernel<<<(NN + 63) / 64, 256, 0, stream>>>(
        hc, aggr,
        wpu + (size_t)l * 96 * 512,
        upd_b1 + l * 128, upd_b2 + l * 128,
        ln_g, ln_b, hn);
    f16* t = hc; hc = hn; hn = t;
  }
  // after 4 swaps: hc == h16a
  gru_kernel<<<(NN + 31) / 32, 256, 0, stream>>>(hc, h_prev, wihT, whhT,
                                                 gru_bih, gru_bhh, (float*)d_out);
}

// Round 7
// 1573.467 us; speedup vs baseline: 1.4544x; 1.4544x over previous
//
#include <hip/hip_runtime.h>
#include <hip/hip_bf16.h>
#include <cstdint>

#define NN 50000
#define NE 800000

typedef _Float16 f16;
typedef f16 f16x8 __attribute__((ext_vector_type(8)));
typedef f16 f16x4 __attribute__((ext_vector_type(4)));
typedef float f32x4 __attribute__((ext_vector_type(4)));

#define TB_STR 136   // f16 stride for [64][128] intermediate (272B)

// ============================================================================
// CSR build: dst-sorted edge permutation (rebuilt every call; graph-safe)
// ============================================================================
__global__ void hist_kernel(const int* __restrict__ edst, int* __restrict__ deg) {
  int e = blockIdx.x * 256 + threadIdx.x;
  if (e < NE) atomicAdd(&deg[edst[e]], 1);
}

// single-block exclusive scan over deg[0..n) -> offs[0..n], offs[n]=total
__global__ void scan_kernel(const int* __restrict__ deg, int* __restrict__ offs, int n) {
  __shared__ int tmp[256];
  __shared__ int carry;
  const int tid = threadIdx.x;
  if (tid == 0) carry = 0;
  __syncthreads();
  for (int base = 0; base < n; base += 1024) {
    int v[4]; int s = 0;
#pragma unroll
    for (int j = 0; j < 4; ++j) {
      int idx = base + tid * 4 + j;
      v[j] = (idx < n) ? deg[idx] : 0;
      s += v[j];
    }
    tmp[tid] = s;
    __syncthreads();
    for (int ofs = 1; ofs < 256; ofs <<= 1) {
      int t = (tid >= ofs) ? tmp[tid - ofs] : 0;
      __syncthreads();
      tmp[tid] += t;
      __syncthreads();
    }
    int excl = carry + tmp[tid] - s;   // exclusive prefix at base+tid*4
#pragma unroll
    for (int j = 0; j < 4; ++j) {
      int idx = base + tid * 4 + j;
      if (idx < n) offs[idx] = excl;
      excl += v[j];
    }
    __syncthreads();
    if (tid == 255) carry += tmp[255];
    __syncthreads();
  }
  if (tid == 0) offs[n] = carry;
}

__global__ void copy_cursor_kernel(const int* __restrict__ offs, int* __restrict__ cursor) {
  int i = blockIdx.x * 256 + threadIdx.x;
  if (i < NN) cursor[i] = offs[i];
}

__global__ void fill_kernel(const int* __restrict__ edst, int* __restrict__ cursor,
                            int* __restrict__ eord) {
  int e = blockIdx.x * 256 + threadIdx.x;
  if (e < NE) {
    int p = atomicAdd(&cursor[edst[e]], 1);
    eord[p] = e;
  }
}

// permute edge arrays into sorted order; edge_attr -> f16 in sorted order
__global__ void permute_kernel(const int* __restrict__ eord,
                               const int* __restrict__ esrc,
                               const int* __restrict__ edst,
                               const float* __restrict__ ea,
                               int* __restrict__ dstp, int* __restrict__ esp,
                               f16* __restrict__ ea16p) {
  int i = blockIdx.x * 256 + threadIdx.x;
  if (i >= NE) return;
  int e = eord[i];
  dstp[i] = edst[e];
  esp[i] = esrc[e];
  const float* sp = ea + (size_t)e * 32;
  f16* dp = ea16p + (size_t)i * 32;
#pragma unroll
  for (int j = 0; j < 4; ++j) {
    float4 u0 = *(const float4*)(sp + j * 8), u1 = *(const float4*)(sp + j * 8 + 4);
    f16x8 v = {(f16)u0.x, (f16)u0.y, (f16)u0.z, (f16)u0.w,
               (f16)u1.x, (f16)u1.y, (f16)u1.z, (f16)u1.w};
    *(f16x8*)(dp + j * 8) = v;
  }
}

// ============================================================================
// Weight pre-pack (f16 MFMA fragment layout; A/B frag layouts symmetric).
// unit = kc*8 + ct ; element [lane][i] = W[kc*32 + (lane>>4)*8 + i][ct*16 + (lane&15)]
// ============================================================================
__global__ void pack_w_kernel(const float* __restrict__ et_w1,
                              const float* __restrict__ et_w2,
                              const float* __restrict__ msg_w1,
                              const float* __restrict__ msg_w2,
                              f16* __restrict__ wpack) {
  int idx = blockIdx.x * 256 + threadIdx.x;
  if (idx >= 4 * 86016) return;
  int l = idx / 86016;
  int rem = idx - l * 86016;
  int unit = rem >> 9;
  int e = rem & 511;
  int ln = e >> 3, i = e & 7;
  const float* src;
  int ul;
  if (unit < 72)       { src = et_w1  + (size_t)l * 288 * 128; ul = unit; }
  else if (unit < 104) { src = et_w2  + (size_t)l * 128 * 128; ul = unit - 72; }
  else if (unit < 136) { src = msg_w1 + (size_t)l * 128 * 128; ul = unit - 104; }
  else                 { src = msg_w2 + (size_t)l * 128 * 128; ul = unit - 136; }
  int kc = ul >> 3, ct = ul & 7;
  int k = kc * 32 + (ln >> 4) * 8 + i;
  int col = ct * 16 + (ln & 15);
  wpack[idx] = (f16)src[k * 128 + col];
}

__global__ void pack_upd_kernel(const float* __restrict__ upd_w1,
                                const float* __restrict__ upd_w2,
                                f16* __restrict__ wpu) {
  int idx = blockIdx.x * 256 + threadIdx.x;
  if (idx >= 4 * 96 * 512) return;
  int l = idx / (96 * 512);
  int rem = idx - l * (96 * 512);
  int unit = rem >> 9, e = rem & 511, ln = e >> 3, i = e & 7;
  const float* src;
  int ul;
  if (unit < 64) { src = upd_w1 + (size_t)l * 256 * 128; ul = unit; }
  else           { src = upd_w2 + (size_t)l * 128 * 128; ul = unit - 64; }
  int kc = ul >> 3, ct = ul & 7;
  int k = kc * 32 + (ln >> 4) * 8 + i;
  int col = ct * 16 + (ln & 15);
  wpu[idx] = (f16)src[k * 128 + col];
}

// ============================================================================
// Edge kernel (dst-sorted edges). D-normal orientation, wave (wr,wc):
// rows wr*32..+32, cols wc*64..+64. acc[rt][ct].
// C/D: lane holds col=ct*16+cl, rows rt*16+kh*4+{0..3}.
// Aggregation: in-LDS run reduction over sorted dst; plain f32 store for
// interior runs, f32 unsafeAtomicAdd for segment-boundary runs.
// ============================================================================
#define EDGE_ACC_INIT(BIAS)                                                    \
  _Pragma("unroll") for (int ct = 0; ct < 4; ++ct) {                           \
    float bv_ = (BIAS)[wc * 64 + ct * 16 + cl];                                \
    acc[0][ct] = (f32x4){bv_, bv_, bv_, bv_};                                  \
    acc[1][ct] = acc[0][ct];                                                   \
  }

#define EDGE_MFMA_KC(A0, A1, UNIT)                                             \
  _Pragma("unroll") for (int ct = 0; ct < 4; ++ct) {                           \
    f16x8 b_ = *(const f16x8*)&wp[(size_t)(((UNIT) + wc * 4 + ct) * 64 + lane) * 8]; \
    acc[0][ct] = __builtin_amdgcn_mfma_f32_16x16x32_f16(A0, b_, acc[0][ct], 0, 0, 0); \
    acc[1][ct] = __builtin_amdgcn_mfma_f32_16x16x32_f16(A1, b_, acc[1][ct], 0, 0, 0); \
  }

#define EDGE_GEMM_LDS(APTR, UNIT0, BIAS)                                       \
  {                                                                            \
    EDGE_ACC_INIT(BIAS);                                                       \
    _Pragma("unroll") for (int kc = 0; kc < 4; ++kc) {                         \
      f16x8 a0_ = *(const f16x8*)&(APTR)[(wr * 32 + cl) * TB_STR + kc * 32 + kh * 8]; \
      f16x8 a1_ = *(const f16x8*)&(APTR)[(wr * 32 + 16 + cl) * TB_STR + kc * 32 + kh * 8]; \
      EDGE_MFMA_KC(a0_, a1_, (UNIT0) + kc * 8);                                \
    }                                                                          \
  }

#define EDGE_STORE(DST, RELU)                                                  \
  _Pragma("unroll") for (int rt = 0; rt < 2; ++rt)                             \
    _Pragma("unroll") for (int ct = 0; ct < 4; ++ct)                           \
      _Pragma("unroll") for (int i = 0; i < 4; ++i) {                          \
        float v_ = acc[rt][ct][i];                                             \
        if (RELU) v_ = fmaxf(v_, 0.f);                                         \
        (DST)[(wr * 32 + rt * 16 + kh * 4 + i) * TB_STR + wc * 64 + ct * 16 + cl] = (f16)v_; \
      }

__global__ __launch_bounds__(256, 6)
void edge_mfma_kernel(const f16* __restrict__ h16, const f16* __restrict__ ea16p,
                      const int* __restrict__ esp, const int* __restrict__ dstp,
                      const f16* __restrict__ wp,
                      const float* __restrict__ b1, const float* __restrict__ b2,
                      const float* __restrict__ b3, const float* __restrict__ b4,
                      float* __restrict__ aggrf) {
  __shared__ f16 buf[64 * TB_STR];
  __shared__ int eidx[128];       // [0:64) dst (sorted), [64:128) src
  const int tid = threadIdx.x;
  const int lane = tid & 63;
  const int wv = tid >> 6;
  const int wr = wv >> 1, wc = wv & 1;
  const int cl = lane & 15;
  const int kh = lane >> 4;
  const int e0 = blockIdx.x * 64;
  if (tid < 64) eidx[tid] = dstp[e0 + tid];
  else if (tid < 128) eidx[tid] = esp[e0 + tid - 64];
  __syncthreads();

  const int r0 = wr * 32 + cl, r1 = r0 + 16;
  const f16* pd0 = h16 + (size_t)eidx[r0] * 128 + kh * 8;       // x_i = h[dst] (sorted: L1-hot)
  const f16* pd1 = h16 + (size_t)eidx[r1] * 128 + kh * 8;
  const f16* ps0 = h16 + (size_t)eidx[64 + r0] * 128 + kh * 8;  // x_j = h[src]
  const f16* ps1 = h16 + (size_t)eidx[64 + r1] * 128 + kh * 8;
  const f16* pe0 = ea16p + (size_t)(e0 + r0) * 32 + kh * 8;
  const f16* pe1 = ea16p + (size_t)(e0 + r1) * 32 + kh * 8;

  f32x4 acc[2][4];
  // ---- GEMM1: et hidden, K=288, A direct from global ----
  EDGE_ACC_INIT(b1);
#pragma unroll
  for (int kc = 0; kc < 4; ++kc) {                  // k in [0,128): h[dst]
    f16x8 a0_ = *(const f16x8*)(pd0 + kc * 32);
    f16x8 a1_ = *(const f16x8*)(pd1 + kc * 32);
    EDGE_MFMA_KC(a0_, a1_, kc * 8);
  }
#pragma unroll
  for (int kc = 4; kc < 8; ++kc) {                  // k in [128,256): h[src]
    f16x8 a0_ = *(const f16x8*)(ps0 + (kc - 4) * 32);
    f16x8 a1_ = *(const f16x8*)(ps1 + (kc - 4) * 32);
    EDGE_MFMA_KC(a0_, a1_, kc * 8);
  }
  {                                                  // k in [256,288): ea16p
    f16x8 a0_ = *(const f16x8*)pe0;
    f16x8 a1_ = *(const f16x8*)pe1;
    EDGE_MFMA_KC(a0_, a1_, 64);
  }
  EDGE_STORE(buf, 1);
  __syncthreads();
  // ---- GEMM2: e_emb, K=128 ----
  EDGE_GEMM_LDS(buf, 72, b2);
  __syncthreads();
  EDGE_STORE(buf, 0);
  __syncthreads();
  // ---- GEMM3: msg hidden, K=128 ----
  EDGE_GEMM_LDS(buf, 104, b3);
  __syncthreads();
  EDGE_STORE(buf, 1);
  __syncthreads();
  // ---- GEMM4: msg, K=128 ----
  EDGE_GEMM_LDS(buf, 136, b4);
  __syncthreads();                 // buf reads done
  EDGE_STORE(buf, 0);              // msg (f16) into buf
  __syncthreads();
  // ---- run-reduction scatter over sorted dst ----
  {
    const int c = tid & 127;            // column 0..127
    const int rbeg = (tid >> 7) * 32;   // segment: rows [rbeg, rbeg+32)
    float sum = 0.f;
    int cur = eidx[rbeg];
    bool openL = true;                  // first run may continue before segment
    for (int r = rbeg; r < rbeg + 32; ++r) {
      sum += (float)buf[r * TB_STR + c];
      bool last = (r == rbeg + 31);
      int nxt = last ? -1 : eidx[r + 1];
      if (last || nxt != cur) {
        float* ap = aggrf + (size_t)cur * 128 + c;
        if (openL || last) unsafeAtomicAdd(ap, sum);   // may span segment/block
        else *ap = sum;                                 // sole writer
        sum = 0.f; cur = nxt; openL = false;
      }
    }
  }
}

// ============================================================================
// Transposed-D MFMA machinery (update kernel; no atomics there)
// ============================================================================
#define MFMA_T(APTR, ASTR, ASWZ, NKC, UNIT0, BIAS)                             \
  {                                                                            \
    _Pragma("unroll") for (int nt = 0; nt < 2; ++nt) {                         \
      f32x4 bv_ = *(const f32x4*)((BIAS) + wv * 32 + nt * 16 + kh * 4);        \
      _Pragma("unroll") for (int et = 0; et < 4; ++et) acc[nt][et] = bv_;      \
    }                                                                          \
    _Pragma("unroll 2") for (int kc = 0; kc < (NKC); ++kc) {                   \
      f16x8 wfr_[2];                                                           \
      _Pragma("unroll") for (int nt = 0; nt < 2; ++nt)                         \
        wfr_[nt] = *(const f16x8*)&wp[(size_t)(((UNIT0) + kc * 8 + wv * 2 + nt) * 64 + lane) * 8]; \
      _Pragma("unroll") for (int et = 0; et < 4; ++et) {                       \
        int r_ = et * 16 + cl;                                                 \
        int idx_ = r_ * (ASTR) + kc * 32 + kh * 8;                             \
        if (ASWZ) idx_ ^= ((r_ & 7) << 3);                                     \
        f16x8 efr_ = *(const f16x8*)&(APTR)[idx_];                             \
        _Pragma("unroll") for (int nt = 0; nt < 2; ++nt)                       \
          acc[nt][et] = __builtin_amdgcn_mfma_f32_16x16x32_f16(wfr_[nt], efr_, acc[nt][et], 0, 0, 0); \
      }                                                                        \
    }                                                                          \
  }

#define STORE_T(DPTR, RELU)                                                    \
  _Pragma("unroll") for (int nt = 0; nt < 2; ++nt)                             \
    _Pragma("unroll") for (int et = 0; et < 4; ++et) {                         \
      float v0_ = acc[nt][et][0], v1_ = acc[nt][et][1],                        \
            v2_ = acc[nt][et][2], v3_ = acc[nt][et][3];                        \
      if (RELU) { v0_ = fmaxf(v0_, 0.f); v1_ = fmaxf(v1_, 0.f);                \
                  v2_ = fmaxf(v2_, 0.f); v3_ = fmaxf(v3_, 0.f); }              \
      int r_ = et * 16 + cl;                                                   \
      int idx_ = (r_ * 128 + wv * 32 + nt * 16 + kh * 4) ^ ((r_ & 7) << 3);    \
      *(f16x4*)&(DPTR)[idx_] = (f16x4){(f16)v0_, (f16)v1_, (f16)v2_, (f16)v3_};\
    }

// ============================================================================
// update: h' = LN(h + MLP2([h|aggr]))  -- f16 MFMA, aggr is f32
// ============================================================================
__global__ __launch_bounds__(256, 2)
void update_mfma_kernel(const f16* __restrict__ h16, const float* __restrict__ aggr,
                        const f16* __restrict__ wp,
                        const float* __restrict__ b1, const float* __restrict__ b2,
                        const float* __restrict__ lng, const float* __restrict__ lnb,
                        f16* __restrict__ h16out) {
  __shared__ f16 ua[64 * 264];
  __shared__ f16 tb[64 * 128];
  __shared__ f16 emb[64 * 128];
  const int tid = threadIdx.x;
  const int lane = tid & 63;
  const int wv = tid >> 6;
  const int cl = lane & 15;
  const int kh = lane >> 4;
  const int r0 = blockIdx.x * 64;
#pragma unroll
  for (int it = 0; it < 8; ++it) {
    int f = tid + it * 256;
    int row = f >> 5, c8 = f & 31;
    int grow = r0 + row;
    f16x8 v = {};
    if (grow < NN) {
      if (c8 < 16) {
        v = *(const f16x8*)(h16 + (size_t)grow * 128 + c8 * 8);
      } else {
        const float* sp = aggr + (size_t)grow * 128 + (c8 - 16) * 8;
        float4 u0 = *(const float4*)sp, u1 = *(const float4*)(sp + 4);
        v = (f16x8){(f16)u0.x, (f16)u0.y, (f16)u0.z, (f16)u0.w,
                    (f16)u1.x, (f16)u1.y, (f16)u1.z, (f16)u1.w};
      }
    }
    *(f16x8*)&ua[row * 264 + c8 * 8] = v;
  }
  __syncthreads();
  f32x4 acc[2][4];
  MFMA_T(ua, 264, 0, 8, 0, b1);             // upd hidden, K=256
  STORE_T(tb, 1);
  __syncthreads();
  MFMA_T(tb, 128, 1, 4, 64, b2);            // h_new, K=128
  STORE_T(emb, 0);
  __syncthreads();
  {
    const int row = tid >> 2, q = tid & 3;
    const int grow = r0 + row;
    float y[32];
    float s = 0.f, ss = 0.f;
#pragma unroll
    for (int j = 0; j < 4; ++j) {
      int col = q * 32 + j * 8;
      int ei = (row * 128 + col) ^ ((row & 7) << 3);
      f16x8 ev = *(const f16x8*)&emb[ei];
      f16x8 rv = *(const f16x8*)&ua[row * 264 + col];
#pragma unroll
      for (int e = 0; e < 8; ++e) {
        float t = (float)ev[e] + (float)rv[e];
        y[j * 8 + e] = t; s += t; ss += t * t;
      }
    }
    s += __shfl_xor(s, 1);  s += __shfl_xor(s, 2);
    ss += __shfl_xor(ss, 1); ss += __shfl_xor(ss, 2);
    float mean = s * (1.f / 128.f);
    float var = ss * (1.f / 128.f) - mean * mean;
    float rstd = rsqrtf(var + 1e-5f);
    if (grow < NN) {
#pragma unroll
      for (int j = 0; j < 4; ++j) {
        int col = q * 32 + j * 8;
        const float4 g0 = *(const float4*)(lng + col), g1 = *(const float4*)(lng + col + 4);
        const float4 q0 = *(const float4*)(lnb + col), q1 = *(const float4*)(lnb + col + 4);
        float gv[8] = {g0.x, g0.y, g0.z, g0.w, g1.x, g1.y, g1.z, g1.w};
        float bv[8] = {q0.x, q0.y, q0.z, q0.w, q1.x, q1.y, q1.z, q1.w};
        f16x8 o;
#pragma unroll
        for (int e = 0; e < 8; ++e)
          o[e] = (f16)((y[j * 8 + e] - mean) * rstd * gv[e] + bv[e]);
        *(f16x8*)(h16out + (size_t)grow * 128 + col) = o;
      }
    }
  }
}

// ============================================================================
// fp32 register-tiled machinery (encoder only)
// ============================================================================
#define ACC_INIT(BPTR)                                                        \
  {                                                                           \
    const float4 bA_ = *(const float4*)((BPTR) + cg * 8);                     \
    const float4 bB_ = *(const float4*)((BPTR) + cg * 8 + 4);                 \
    _Pragma("unroll") for (int i_ = 0; i_ < 4; ++i_) {                        \
      acc[i_][0] = bA_.x; acc[i_][1] = bA_.y; acc[i_][2] = bA_.z;             \
      acc[i_][3] = bA_.w; acc[i_][4] = bB_.x; acc[i_][5] = bB_.y;             \
      acc[i_][6] = bB_.z; acc[i_][7] = bB_.w;                                 \
    }                                                                         \
  }

#define GEMM_STEP(ABUF, ASTR, WPTR)                                           \
  {                                                                           \
    const float4 w0_ = *(const float4*)((WPTR) + (size_t)k * 128 + cg * 8);   \
    const float4 w1_ = *(const float4*)((WPTR) + (size_t)k * 128 + cg * 8 + 4);\
    float wv_[8] = {w0_.x, w0_.y, w0_.z, w0_.w, w1_.x, w1_.y, w1_.z, w1_.w};  \
    float av_[4];                                                             \
    _Pragma("unroll") for (int i_ = 0; i_ < 4; ++i_)                          \
        av_[i_] = (ABUF)[(rg * 4 + i_) * (ASTR) + k];                         \
    _Pragma("unroll") for (int i_ = 0; i_ < 4; ++i_)                          \
      _Pragma("unroll") for (int j_ = 0; j_ < 8; ++j_)                        \
          acc[i_][j_] = fmaf(av_[i_], wv_[j_], acc[i_][j_]);                  \
  }

#define STORE_LDS_RELU(TBUF, TSTR)                                            \
  _Pragma("unroll") for (int i_ = 0; i_ < 4; ++i_) {                          \
    *(float4*)&(TBUF)[(rg * 4 + i_) * (TSTR) + cg * 8] =                      \
        make_float4(fmaxf(acc[i_][0], 0.f), fmaxf(acc[i_][1], 0.f),           \
                    fmaxf(acc[i_][2], 0.f), fmaxf(acc[i_][3], 0.f));          \
    *(float4*)&(TBUF)[(rg * 4 + i_) * (TSTR) + cg * 8 + 4] =                  \
        make_float4(fmaxf(acc[i_][4], 0.f), fmaxf(acc[i_][5], 0.f),           \
                    fmaxf(acc[i_][6], 0.f), fmaxf(acc[i_][7], 0.f));          \
  }

__global__ void gru_transpose_kernel(const float* __restrict__ wih,
                                     const float* __restrict__ whh,
                                     float* __restrict__ wihT,
                                     float* __restrict__ whhT) {
  int idx = blockIdx.x * 256 + threadIdx.x;
  if (idx < 128 * 384) {
    int k = idx / 384;
    int j = idx - k * 384;
    wihT[idx] = wih[j * 128 + k];
    whhT[idx] = whh[j * 128 + k];
  }
}

__global__ __launch_bounds__(256, 2)
void encoder_kernel(const float* __restrict__ x,
                    const float* __restrict__ w1, const float* __restrict__ b1,
                    const float* __restrict__ w2, const float* __restrict__ b2,
                    f16* __restrict__ h16out) {
  __shared__ float xa[64 * 132];
  __shared__ float tb[64 * 132];
  const int tid = threadIdx.x;
  const int cg = tid & 15, rg = tid >> 4;
  const int r0 = blockIdx.x * 64;
#pragma unroll
  for (int it = 0; it < 8; ++it) {
    int f = tid + it * 256;
    int row = f >> 5, c4 = f & 31;
    float4 v = make_float4(0.f, 0.f, 0.f, 0.f);
    int grow = r0 + row;
    if (grow < NN) v = *(const float4*)(x + (size_t)grow * 128 + c4 * 4);
    *(float4*)&xa[row * 132 + c4 * 4] = v;
  }
  __syncthreads();
  float acc[4][8];
  ACC_INIT(b1);
#pragma unroll 2
  for (int k = 0; k < 128; ++k) GEMM_STEP(xa, 132, w1);
  STORE_LDS_RELU(tb, 132);
  __syncthreads();
  ACC_INIT(b2);
#pragma unroll 2
  for (int k = 0; k < 128; ++k) GEMM_STEP(tb, 132, w2);
#pragma unroll
  for (int i = 0; i < 4; ++i) {
    int grow = r0 + rg * 4 + i;
    if (grow < NN) {
      f16x8 o = {(f16)acc[i][0], (f16)acc[i][1], (f16)acc[i][2], (f16)acc[i][3],
                 (f16)acc[i][4], (f16)acc[i][5], (f16)acc[i][6], (f16)acc[i][7]};
      *(f16x8*)(h16out + (size_t)grow * 128 + cg * 8) = o;
    }
  }
}

__global__ __launch_bounds__(256, 4)
void gru_kernel(const f16* __restrict__ h16, const float* __restrict__ hprev,
                const float* __restrict__ wihT, const float* __restrict__ whhT,
                const float* __restrict__ bih, const float* __restrict__ bhh,
                float* __restrict__ out) {
  __shared__ float ha[32 * 132];
  __shared__ float hp[32 * 132];
  const int tid = threadIdx.x, cg = tid & 15, rg = tid >> 4;
  const int r0 = blockIdx.x * 32;
#pragma unroll
  for (int it = 0; it < 2; ++it) {
    int f = tid + it * 256;
    int row = f >> 4, c8 = f & 15;
    int grow = r0 + row;
    f16x8 v = {};
    if (grow < NN) v = *(const f16x8*)(h16 + (size_t)grow * 128 + c8 * 8);
    float* dp = &ha[row * 132 + c8 * 8];
    *(float4*)dp = make_float4((float)v[0], (float)v[1], (float)v[2], (float)v[3]);
    *(float4*)(dp + 4) = make_float4((float)v[4], (float)v[5], (float)v[6], (float)v[7]);
  }
#pragma unroll
  for (int it = 0; it < 4; ++it) {
    int f = tid + it * 256;
    int row = f >> 5, c4 = f & 31;
    int grow = r0 + row;
    float4 vp = make_float4(0.f, 0.f, 0.f, 0.f);
    if (grow < NN) vp = *(const float4*)(hprev + (size_t)grow * 128 + c4 * 4);
    *(float4*)&hp[row * 132 + c4 * 4] = vp;
  }
  __syncthreads();
  float rgate[2][8], zgate[2][8];
#pragma unroll
  for (int c = 0; c < 2; ++c) {
    float acc[2][8];
#pragma unroll
    for (int j = 0; j < 8; ++j) {
      float bsum = bih[c * 128 + cg * 8 + j] + bhh[c * 128 + cg * 8 + j];
      acc[0][j] = bsum; acc[1][j] = bsum;
    }
    for (int k = 0; k < 128; ++k) {
      const float* wi = wihT + (size_t)k * 384 + c * 128 + cg * 8;
      const float* wh = whhT + (size_t)k * 384 + c * 128 + cg * 8;
      const float4 wi0 = *(const float4*)wi, wi1 = *(const float4*)(wi + 4);
      const float4 wh0 = *(const float4*)wh, wh1 = *(const float4*)(wh + 4);
      float wiv[8] = {wi0.x, wi0.y, wi0.z, wi0.w, wi1.x, wi1.y, wi1.z, wi1.w};
      float whv[8] = {wh0.x, wh0.y, wh0.z, wh0.w, wh1.x, wh1.y, wh1.z, wh1.w};
      float a0 = ha[(rg * 2 + 0) * 132 + k], a1 = ha[(rg * 2 + 1) * 132 + k];
      float p0 = hp[(rg * 2 + 0) * 132 + k], p1 = hp[(rg * 2 + 1) * 132 + k];
#pragma unroll
      for (int j = 0; j < 8; ++j) {
        acc[0][j] = fmaf(a0, wiv[j], acc[0][j]);
        acc[1][j] = fmaf(a1, wiv[j], acc[1][j]);
        acc[0][j] = fmaf(p0, whv[j], acc[0][j]);
        acc[1][j] = fmaf(p1, whv[j], acc[1][j]);
      }
    }
#pragma unroll
    for (int i = 0; i < 2; ++i)
#pragma unroll
      for (int j = 0; j < 8; ++j) {
        float sg = 1.f / (1.f + __expf(-acc[i][j]));
        if (c == 0) rgate[i][j] = sg; else zgate[i][j] = sg;
      }
  }
  float ai[2][8], ah[2][8];
#pragma unroll
  for (int j = 0; j < 8; ++j) {
    float bi = bih[256 + cg * 8 + j], bh = bhh[256 + cg * 8 + j];
    ai[0][j] = bi; ai[1][j] = bi;
    ah[0][j] = bh; ah[1][j] = bh;
  }
  for (int k = 0; k < 128; ++k) {
    const float* wi = wihT + (size_t)k * 384 + 256 + cg * 8;
    const float* wh = whhT + (size_t)k * 384 + 256 + cg * 8;
    const float4 wi0 = *(const float4*)wi, wi1 = *(const float4*)(wi + 4);
    const float4 wh0 = *(const float4*)wh, wh1 = *(const float4*)(wh + 4);
    float wiv[8] = {wi0.x, wi0.y, wi0.z, wi0.w, wi1.x, wi1.y, wi1.z, wi1.w};
    float whv[8] = {wh0.x, wh0.y, wh0.z, wh0.w, wh1.x, wh1.y, wh1.z, wh1.w};
    float a0 = ha[(rg * 2 + 0) * 132 + k], a1 = ha[(rg * 2 + 1) * 132 + k];
    float p0 = hp[(rg * 2 + 0) * 132 + k], p1 = hp[(rg * 2 + 1) * 132 + k];
#pragma unroll
    for (int j = 0; j < 8; ++j) {
      ai[0][j] = fmaf(a0, wiv[j], ai[0][j]);
      ai[1][j] = fmaf(a1, wiv[j], ai[1][j]);
      ah[0][j] = fmaf(p0, whv[j], ah[0][j]);
      ah[1][j] = fmaf(p1, whv[j], ah[1][j]);
    }
  }
#pragma unroll
  for (int i = 0; i < 2; ++i) {
    int grow = r0 + rg * 2 + i;
    if (grow >= NN) continue;
    float o[8];
#pragma unroll
    for (int j = 0; j < 8; ++j) {
      float nn_ = tanhf(fmaf(rgate[i][j], ah[i][j], ai[i][j]));
      float hpv = hp[(rg * 2 + i) * 132 + cg * 8 + j];
      o[j] = (1.f - zgate[i][j]) * nn_ + zgate[i][j] * hpv;
    }
    *(float4*)(out + (size_t)grow * 128 + cg * 8) = make_float4(o[0], o[1], o[2], o[3]);
    *(float4*)(out + (size_t)grow * 128 + cg * 8 + 4) = make_float4(o[4], o[5], o[6], o[7]);
  }
}

// ---------------- launch ----------------
extern "C" void kernel_launch(void* const* d_in, const int* in_sizes, int n_in,
                              void* d_out, int out_size, void* d_ws, size_t ws_size,
                              hipStream_t stream) {
  (void)in_sizes; (void)n_in; (void)out_size; (void)ws_size;
  const float* x         = (const float*)d_in[0];
  const float* edge_attr = (const float*)d_in[1];
  const float* h_prev    = (const float*)d_in[2];
  const float* enc_w1    = (const float*)d_in[3];
  const float* enc_b1    = (const float*)d_in[4];
  const float* enc_w2    = (const float*)d_in[5];
  const float* enc_b2    = (const float*)d_in[6];
  const float* et_w1     = (const float*)d_in[7];
  const float* et_b1     = (const float*)d_in[8];
  const float* et_w2     = (const float*)d_in[9];
  const float* et_b2     = (const float*)d_in[10];
  const float* msg_w1    = (const float*)d_in[11];
  const float* msg_b1    = (const float*)d_in[12];
  const float* msg_w2    = (const float*)d_in[13];
  const float* msg_b2    = (const float*)d_in[14];
  const float* upd_w1    = (const float*)d_in[15];
  const float* upd_b1    = (const float*)d_in[16];
  const float* upd_w2    = (const float*)d_in[17];
  const float* upd_b2    = (const float*)d_in[18];
  const float* ln_g      = (const float*)d_in[19];
  const float* ln_b      = (const float*)d_in[20];
  const float* gru_wih   = (const float*)d_in[21];
  const float* gru_whh   = (const float*)d_in[22];
  const float* gru_bih   = (const float*)d_in[23];
  const float* gru_bhh   = (const float*)d_in[24];
  const int* edge_index  = (const int*)d_in[25];
  const int* esrc = edge_index;        // edge_index[0]
  const int* edst = edge_index + NE;   // edge_index[1]

  // workspace layout (same footprint as R5/R6: ~99 MB)
  float* ws    = (float*)d_ws;
  float* aggrf = ws;                                 // N*128 f32
  float* wihT  = ws + (size_t)NN * 128;              // 128*384
  float* whhT  = wihT + 128 * 384;                   // 128*384
  f16*   h16a  = (f16*)(whhT + 128 * 384);           // N*128 f16
  f16*   h16b  = h16a + (size_t)NN * 128;            // N*128 f16
  f16*   wpe   = h16b + (size_t)NN * 128;            // 4*168*512 f16
  f16*   wpu   = wpe + 4 * 86016;                    // 4*96*512 f16
  f16*   ea16p = wpu + 4 * 96 * 512;                 // E*32 f16 (dst-sorted)

  // CSR scratch in d_out (10.2 MB of 25.6 MB; fully overwritten by gru at end)
  int* iout   = (int*)d_out;
  int* deg    = iout;                  // NN
  int* offs   = iout + 51200;          // NN+1
  int* cursor = iout + 102400;         // NN
  int* eord   = iout + 153600;         // NE
  int* dstp   = iout + 153600 + NE;    // NE
  int* esp    = iout + 153600 + 2 * NE; // NE  (ends at 2,553,600 ints < 6.4M)

  // ---- CSR build (every call; deterministic result) ----
  hipMemsetAsync(deg, 0, NN * sizeof(int), stream);
  hist_kernel<<<(NE + 255) / 256, 256, 0, stream>>>(edst, deg);
  scan_kernel<<<1, 256, 0, stream>>>(deg, offs, NN);
  copy_cursor_kernel<<<(NN + 255) / 256, 256, 0, stream>>>(offs, cursor);
  fill_kernel<<<(NE + 255) / 256, 256, 0, stream>>>(edst, cursor, eord);
  permute_kernel<<<(NE + 255) / 256, 256, 0, stream>>>(eord, esrc, edst, edge_attr,
                                                       dstp, esp, ea16p);

  // ---- weights / encoder ----
  gru_transpose_kernel<<<192, 256, 0, stream>>>(gru_wih, gru_whh, wihT, whhT);
  pack_w_kernel<<<(4 * 86016 + 255) / 256, 256, 0, stream>>>(et_w1, et_w2, msg_w1, msg_w2, wpe);
  pack_upd_kernel<<<(4 * 96 * 512 + 255) / 256, 256, 0, stream>>>(upd_w1, upd_w2, wpu);
  encoder_kernel<<<(NN + 63) / 64, 256, 0, stream>>>(x, enc_w1, enc_b1, enc_w2, enc_b2, h16a);

  f16* hc = h16a;
  f16* hn = h16b;
  for (int l = 0; l < 4; ++l) {
    hipMemsetAsync(aggrf, 0, (size_t)NN * 128 * sizeof(float), stream);
    edge_mfma_kernel<<<NE / 64, 256, 0, stream>>>(
        hc, ea16p, esp, dstp,
        wpe + (size_t)l * 86016,
        et_b1 + l * 128, et_b2 + l * 128,
        msg_b1 + l * 128, msg_b2 + l * 128,
        aggrf);
    update_mfma_kernel<<<(NN + 63) / 64, 256, 0, stream>>>(
        hc, aggrf,
        wpu + (size_t)l * 96 * 512,
        upd_b1 + l * 128, upd_b2 + l * 128,
        ln_g, ln_b, hn);
    f16* t = hc; hc = hn; hn = t;
  }
  // after 4 swaps: hc == h16a
  gru_kernel<<<(NN + 31) / 32, 256, 0, stream>>>(hc, h_prev, wihT, whhT,
                                                 gru_bih, gru_bhh, (float*)d_out);
}

// Round 8
// 1259.203 us; speedup vs baseline: 1.8174x; 1.2496x over previous
//
#include <hip/hip_runtime.h>
#include <hip/hip_bf16.h>
#include <cstdint>

#define NN 50000
#define NE 800000

typedef _Float16 f16;
typedef f16 f16x8 __attribute__((ext_vector_type(8)));
typedef f16 f16x4 __attribute__((ext_vector_type(4)));
typedef float f32x4 __attribute__((ext_vector_type(4)));

#define TB_STR 136   // f16 stride for [64][128] intermediate (272B)

// ============================================================================
// CSR build: dst-sorted edge permutation (rebuilt every call; graph-safe)
// ============================================================================
__global__ void hist_kernel(const int* __restrict__ edst, int* __restrict__ deg) {
  int e = blockIdx.x * 256 + threadIdx.x;
  if (e < NE) atomicAdd(&deg[edst[e]], 1);
}

__global__ void scan_kernel(const int* __restrict__ deg, int* __restrict__ offs, int n) {
  __shared__ int tmp[256];
  __shared__ int carry;
  const int tid = threadIdx.x;
  if (tid == 0) carry = 0;
  __syncthreads();
  for (int base = 0; base < n; base += 1024) {
    int v[4]; int s = 0;
#pragma unroll
    for (int j = 0; j < 4; ++j) {
      int idx = base + tid * 4 + j;
      v[j] = (idx < n) ? deg[idx] : 0;
      s += v[j];
    }
    tmp[tid] = s;
    __syncthreads();
    for (int ofs = 1; ofs < 256; ofs <<= 1) {
      int t = (tid >= ofs) ? tmp[tid - ofs] : 0;
      __syncthreads();
      tmp[tid] += t;
      __syncthreads();
    }
    int excl = carry + tmp[tid] - s;
#pragma unroll
    for (int j = 0; j < 4; ++j) {
      int idx = base + tid * 4 + j;
      if (idx < n) offs[idx] = excl;
      excl += v[j];
    }
    __syncthreads();
    if (tid == 255) carry += tmp[255];
    __syncthreads();
  }
  if (tid == 0) offs[n] = carry;
}

__global__ void copy_cursor_kernel(const int* __restrict__ offs, int* __restrict__ cursor) {
  int i = blockIdx.x * 256 + threadIdx.x;
  if (i < NN) cursor[i] = offs[i];
}

__global__ void fill_kernel(const int* __restrict__ edst, int* __restrict__ cursor,
                            int* __restrict__ eord) {
  int e = blockIdx.x * 256 + threadIdx.x;
  if (e < NE) {
    int p = atomicAdd(&cursor[edst[e]], 1);
    eord[p] = e;
  }
}

__global__ void permute_kernel(const int* __restrict__ eord,
                               const int* __restrict__ esrc,
                               const int* __restrict__ edst,
                               const float* __restrict__ ea,
                               int* __restrict__ dstp, int* __restrict__ esp,
                               f16* __restrict__ ea16p) {
  int i = blockIdx.x * 256 + threadIdx.x;
  if (i >= NE) return;
  int e = eord[i];
  dstp[i] = edst[e];
  esp[i] = esrc[e];
  const float* sp = ea + (size_t)e * 32;
  f16* dp = ea16p + (size_t)i * 32;
#pragma unroll
  for (int j = 0; j < 4; ++j) {
    float4 u0 = *(const float4*)(sp + j * 8), u1 = *(const float4*)(sp + j * 8 + 4);
    f16x8 v = {(f16)u0.x, (f16)u0.y, (f16)u0.z, (f16)u0.w,
               (f16)u1.x, (f16)u1.y, (f16)u1.z, (f16)u1.w};
    *(f16x8*)(dp + j * 8) = v;
  }
}

// ============================================================================
// Weight pre-pack (f16 MFMA fragment layout).
// unit = kc*8 + ct ; element [lane][i] = W[kc*32 + (lane>>4)*8 + i][ct*16 + (lane&15)]
// ============================================================================
__global__ void pack_w_kernel(const float* __restrict__ et_w1,
                              const float* __restrict__ et_w2,
                              const float* __restrict__ msg_w1,
                              const float* __restrict__ msg_w2,
                              f16* __restrict__ wpack) {
  int idx = blockIdx.x * 256 + threadIdx.x;
  if (idx >= 4 * 86016) return;
  int l = idx / 86016;
  int rem = idx - l * 86016;
  int unit = rem >> 9;
  int e = rem & 511;
  int ln = e >> 3, i = e & 7;
  const float* src;
  int ul;
  if (unit < 72)       { src = et_w1  + (size_t)l * 288 * 128; ul = unit; }
  else if (unit < 104) { src = et_w2  + (size_t)l * 128 * 128; ul = unit - 72; }
  else if (unit < 136) { src = msg_w1 + (size_t)l * 128 * 128; ul = unit - 104; }
  else                 { src = msg_w2 + (size_t)l * 128 * 128; ul = unit - 136; }
  int kc = ul >> 3, ct = ul & 7;
  int k = kc * 32 + (ln >> 4) * 8 + i;
  int col = ct * 16 + (ln & 15);
  wpack[idx] = (f16)src[k * 128 + col];
}

__global__ void pack_upd_kernel(const float* __restrict__ upd_w1,
                                const float* __restrict__ upd_w2,
                                f16* __restrict__ wpu) {
  int idx = blockIdx.x * 256 + threadIdx.x;
  if (idx >= 4 * 96 * 512) return;
  int l = idx / (96 * 512);
  int rem = idx - l * (96 * 512);
  int unit = rem >> 9, e = rem & 511, ln = e >> 3, i = e & 7;
  const float* src;
  int ul;
  if (unit < 64) { src = upd_w1 + (size_t)l * 256 * 128; ul = unit; }
  else           { src = upd_w2 + (size_t)l * 128 * 128; ul = unit - 64; }
  int kc = ul >> 3, ct = ul & 7;
  int k = kc * 32 + (ln >> 4) * 8 + i;
  int col = ct * 16 + (ln & 15);
  wpu[idx] = (f16)src[k * 128 + col];
}

// GRU pack: units 0..127 = W_rz (K=256 over [h|hp], N=256, torch W^T);
// 128..159 = W_ni (wih rows 256..383); 160..191 = W_nh (whh rows 256..383).
// Also brz[j] = bih[j]+bhh[j] for j<256.
__global__ void pack_gru_kernel(const float* __restrict__ wih,
                                const float* __restrict__ whh,
                                const float* __restrict__ bih,
                                const float* __restrict__ bhh,
                                f16* __restrict__ wg, float* __restrict__ brz) {
  int idx = blockIdx.x * 256 + threadIdx.x;
  if (idx < 256) brz[idx] = bih[idx] + bhh[idx];
  if (idx >= 192 * 512) return;
  int unit = idx >> 9, e = idx & 511, ln = e >> 3, i = e & 7;
  int krow = (ln >> 4) * 8 + i;
  int cl16 = ln & 15;
  f16 val;
  if (unit < 128) {
    int kc = unit >> 4, ctg = unit & 15;
    int k = kc * 32 + krow;
    int col = ctg * 16 + cl16;
    float w = (k < 128) ? wih[col * 128 + k] : whh[col * 128 + (k - 128)];
    val = (f16)w;
  } else if (unit < 160) {
    int ul = unit - 128;
    int k = (ul >> 3) * 32 + krow;
    int col = (ul & 7) * 16 + cl16;
    val = (f16)wih[(256 + col) * 128 + k];
  } else {
    int ul = unit - 160;
    int k = (ul >> 3) * 32 + krow;
    int col = (ul & 7) * 16 + cl16;
    val = (f16)whh[(256 + col) * 128 + k];
  }
  wg[idx] = val;
}

// encoder pack: units 0..31 = enc_w1, 32..63 = enc_w2 (each K=128,N=128)
__global__ void pack_enc_kernel(const float* __restrict__ w1,
                                const float* __restrict__ w2,
                                f16* __restrict__ wpenc) {
  int idx = blockIdx.x * 256 + threadIdx.x;
  if (idx >= 64 * 512) return;
  int unit = idx >> 9, e = idx & 511, ln = e >> 3, i = e & 7;
  const float* src = (unit < 32) ? w1 : w2;
  int ul = unit & 31;
  int k = (ul >> 3) * 32 + (ln >> 4) * 8 + i;
  int col = (ul & 7) * 16 + (ln & 15);
  wpenc[idx] = (f16)src[k * 128 + col];
}

// x -> f16
__global__ void cvt_x_kernel(const float* __restrict__ x, f16* __restrict__ x16) {
  int idx = blockIdx.x * 256 + threadIdx.x;
  if (idx >= NN * 16) return;
  const float* sp = x + (size_t)idx * 8;
  float4 u0 = *(const float4*)sp, u1 = *(const float4*)(sp + 4);
  f16x8 v = {(f16)u0.x, (f16)u0.y, (f16)u0.z, (f16)u0.w,
             (f16)u1.x, (f16)u1.y, (f16)u1.z, (f16)u1.w};
  *(f16x8*)(x16 + (size_t)idx * 8) = v;
}

// ============================================================================
// Shared MFMA tile macros (D-normal). Wave (wr,wc): rows wr*32..+32,
// cols wc*64..+64. acc[rt][ct]. C/D: lane -> col=ct*16+cl, rows rt*16+kh*4+{0..3}.
// ============================================================================
#define EDGE_ACC_INIT(BIAS)                                                    \
  _Pragma("unroll") for (int ct = 0; ct < 4; ++ct) {                           \
    float bv_ = (BIAS)[wc * 64 + ct * 16 + cl];                                \
    acc[0][ct] = (f32x4){bv_, bv_, bv_, bv_};                                  \
    acc[1][ct] = acc[0][ct];                                                   \
  }

#define EDGE_MFMA_KC(A0, A1, UNIT)                                             \
  _Pragma("unroll") for (int ct = 0; ct < 4; ++ct) {                           \
    f16x8 b_ = *(const f16x8*)&wp[(size_t)(((UNIT) + wc * 4 + ct) * 64 + lane) * 8]; \
    acc[0][ct] = __builtin_amdgcn_mfma_f32_16x16x32_f16(A0, b_, acc[0][ct], 0, 0, 0); \
    acc[1][ct] = __builtin_amdgcn_mfma_f32_16x16x32_f16(A1, b_, acc[1][ct], 0, 0, 0); \
  }

#define EDGE_GEMM_LDS(APTR, UNIT0, BIAS)                                       \
  {                                                                            \
    EDGE_ACC_INIT(BIAS);                                                       \
    _Pragma("unroll") for (int kc = 0; kc < 4; ++kc) {                         \
      f16x8 a0_ = *(const f16x8*)&(APTR)[(wr * 32 + cl) * TB_STR + kc * 32 + kh * 8]; \
      f16x8 a1_ = *(const f16x8*)&(APTR)[(wr * 32 + 16 + cl) * TB_STR + kc * 32 + kh * 8]; \
      EDGE_MFMA_KC(a0_, a1_, (UNIT0) + kc * 8);                                \
    }                                                                          \
  }

#define EDGE_STORE(DST, RELU)                                                  \
  _Pragma("unroll") for (int rt = 0; rt < 2; ++rt)                             \
    _Pragma("unroll") for (int ct = 0; ct < 4; ++ct)                           \
      _Pragma("unroll") for (int i = 0; i < 4; ++i) {                          \
        float v_ = acc[rt][ct][i];                                             \
        if (RELU) v_ = fmaxf(v_, 0.f);                                         \
        (DST)[(wr * 32 + rt * 16 + kh * 4 + i) * TB_STR + wc * 64 + ct * 16 + cl] = (f16)v_; \
      }

// ============================================================================
// Edge kernel (dst-sorted edges) + run-reduction scatter (R7, unchanged)
// ============================================================================
__global__ __launch_bounds__(256, 6)
void edge_mfma_kernel(const f16* __restrict__ h16, const f16* __restrict__ ea16p,
                      const int* __restrict__ esp, const int* __restrict__ dstp,
                      const f16* __restrict__ wp,
                      const float* __restrict__ b1, const float* __restrict__ b2,
                      const float* __restrict__ b3, const float* __restrict__ b4,
                      float* __restrict__ aggrf) {
  __shared__ f16 buf[64 * TB_STR];
  __shared__ int eidx[128];
  const int tid = threadIdx.x;
  const int lane = tid & 63;
  const int wv = tid >> 6;
  const int wr = wv >> 1, wc = wv & 1;
  const int cl = lane & 15;
  const int kh = lane >> 4;
  const int e0 = blockIdx.x * 64;
  if (tid < 64) eidx[tid] = dstp[e0 + tid];
  else if (tid < 128) eidx[tid] = esp[e0 + tid - 64];
  __syncthreads();

  const int r0 = wr * 32 + cl, r1 = r0 + 16;
  const f16* pd0 = h16 + (size_t)eidx[r0] * 128 + kh * 8;
  const f16* pd1 = h16 + (size_t)eidx[r1] * 128 + kh * 8;
  const f16* ps0 = h16 + (size_t)eidx[64 + r0] * 128 + kh * 8;
  const f16* ps1 = h16 + (size_t)eidx[64 + r1] * 128 + kh * 8;
  const f16* pe0 = ea16p + (size_t)(e0 + r0) * 32 + kh * 8;
  const f16* pe1 = ea16p + (size_t)(e0 + r1) * 32 + kh * 8;

  f32x4 acc[2][4];
  EDGE_ACC_INIT(b1);
#pragma unroll
  for (int kc = 0; kc < 4; ++kc) {
    f16x8 a0_ = *(const f16x8*)(pd0 + kc * 32);
    f16x8 a1_ = *(const f16x8*)(pd1 + kc * 32);
    EDGE_MFMA_KC(a0_, a1_, kc * 8);
  }
#pragma unroll
  for (int kc = 4; kc < 8; ++kc) {
    f16x8 a0_ = *(const f16x8*)(ps0 + (kc - 4) * 32);
    f16x8 a1_ = *(const f16x8*)(ps1 + (kc - 4) * 32);
    EDGE_MFMA_KC(a0_, a1_, kc * 8);
  }
  {
    f16x8 a0_ = *(const f16x8*)pe0;
    f16x8 a1_ = *(const f16x8*)pe1;
    EDGE_MFMA_KC(a0_, a1_, 64);
  }
  EDGE_STORE(buf, 1);
  __syncthreads();
  EDGE_GEMM_LDS(buf, 72, b2);
  __syncthreads();
  EDGE_STORE(buf, 0);
  __syncthreads();
  EDGE_GEMM_LDS(buf, 104, b3);
  __syncthreads();
  EDGE_STORE(buf, 1);
  __syncthreads();
  EDGE_GEMM_LDS(buf, 136, b4);
  __syncthreads();
  EDGE_STORE(buf, 0);
  __syncthreads();
  {
    const int c = tid & 127;
    const int rbeg = (tid >> 7) * 32;
    float sum = 0.f;
    int cur = eidx[rbeg];
    bool openL = true;
    for (int r = rbeg; r < rbeg + 32; ++r) {
      sum += (float)buf[r * TB_STR + c];
      bool last = (r == rbeg + 31);
      int nxt = last ? -1 : eidx[r + 1];
      if (last || nxt != cur) {
        float* ap = aggrf + (size_t)cur * 128 + c;
        if (openL || last) unsafeAtomicAdd(ap, sum);
        else *ap = sum;
        sum = 0.f; cur = nxt; openL = false;
      }
    }
  }
}

// ============================================================================
// encoder: h16 = f16(relu(x16@W1+b1)@W2+b2)  -- f16 MFMA
// ============================================================================
__global__ __launch_bounds__(256, 4)
void encoder_mfma_kernel(const f16* __restrict__ x16, const f16* __restrict__ wp,
                         const float* __restrict__ b1, const float* __restrict__ b2,
                         f16* __restrict__ h16out) {
  __shared__ f16 buf[64 * TB_STR];
  const int tid = threadIdx.x;
  const int lane = tid & 63;
  const int wv = tid >> 6;
  const int wr = wv >> 1, wc = wv & 1;
  const int cl = lane & 15;
  const int kh = lane >> 4;
  const int r0 = blockIdx.x * 64;
  const int gr0 = min(r0 + wr * 32 + cl, NN - 1);
  const int gr1 = min(r0 + wr * 32 + 16 + cl, NN - 1);
  const f16* px0 = x16 + (size_t)gr0 * 128 + kh * 8;
  const f16* px1 = x16 + (size_t)gr1 * 128 + kh * 8;
  f32x4 acc[2][4];
  EDGE_ACC_INIT(b1);
#pragma unroll
  for (int kc = 0; kc < 4; ++kc) {
    f16x8 a0_ = *(const f16x8*)(px0 + kc * 32);
    f16x8 a1_ = *(const f16x8*)(px1 + kc * 32);
    EDGE_MFMA_KC(a0_, a1_, kc * 8);
  }
  EDGE_STORE(buf, 1);
  __syncthreads();
  EDGE_GEMM_LDS(buf, 32, b2);
  __syncthreads();
  EDGE_STORE(buf, 0);
  __syncthreads();
#pragma unroll
  for (int it = 0; it < 4; ++it) {
    int f = tid + it * 256;
    int row = f >> 4, c8 = f & 15;
    int grow = r0 + row;
    if (grow < NN) {
      f16x8 v = *(const f16x8*)&buf[row * TB_STR + c8 * 8];
      *(f16x8*)(h16out + (size_t)grow * 128 + c8 * 8) = v;
    }
  }
}

// ============================================================================
// GRU cell, f16 MFMA. rz-gates via combined K=256 GEMM over [h|hp];
// n-gate via two K=128 GEMMs fused in-register.
// ============================================================================
__global__ __launch_bounds__(256, 2)
void gru_mfma_kernel(const f16* __restrict__ h16, const float* __restrict__ hprev,
                     const f16* __restrict__ wg, const float* __restrict__ brz,
                     const float* __restrict__ bih, const float* __restrict__ bhh,
                     float* __restrict__ out) {
  __shared__ f16 ac[64 * 264];   // [h | hp] per row (K=256, stride 264)
  __shared__ f16 rz[64 * 264];   // sigmoid outputs: r cols 0..127, z cols 128..255
  const int tid = threadIdx.x;
  const int lane = tid & 63;
  const int wv = tid >> 6;
  const int wr = wv >> 1, wc = wv & 1;
  const int cl = lane & 15;
  const int kh = lane >> 4;
  const int r0 = blockIdx.x * 64;
  // stage [h16 | cvt(hprev)]
#pragma unroll
  for (int it = 0; it < 8; ++it) {
    int f = tid + it * 256;
    int row = f >> 5, c8 = f & 31;
    int grow = r0 + row;
    f16x8 v = {};
    if (grow < NN) {
      if (c8 < 16) {
        v = *(const f16x8*)(h16 + (size_t)grow * 128 + c8 * 8);
      } else {
        const float* sp = hprev + (size_t)grow * 128 + (c8 - 16) * 8;
        float4 u0 = *(const float4*)sp, u1 = *(const float4*)(sp + 4);
        v = (f16x8){(f16)u0.x, (f16)u0.y, (f16)u0.z, (f16)u0.w,
                    (f16)u1.x, (f16)u1.y, (f16)u1.z, (f16)u1.w};
      }
    }
    *(f16x8*)&ac[row * 264 + c8 * 8] = v;
  }
  __syncthreads();
  // ---- G_rz: [64,256]@[256,256]; wave wv owns cols wv*64..+64, all 64 rows ----
  {
    f32x4 az[4][4];
#pragma unroll
    for (int ct = 0; ct < 4; ++ct) {
      float bv = brz[wv * 64 + ct * 16 + cl];
#pragma unroll
      for (int rt = 0; rt < 4; ++rt) az[rt][ct] = (f32x4){bv, bv, bv, bv};
    }
#pragma unroll
    for (int kc = 0; kc < 8; ++kc) {
      f16x8 a_[4];
#pragma unroll
      for (int rt = 0; rt < 4; ++rt)
        a_[rt] = *(const f16x8*)&ac[(rt * 16 + cl) * 264 + kc * 32 + kh * 8];
#pragma unroll
      for (int ct = 0; ct < 4; ++ct) {
        f16x8 b_ = *(const f16x8*)&wg[(size_t)((kc * 16 + wv * 4 + ct) * 64 + lane) * 8];
#pragma unroll
        for (int rt = 0; rt < 4; ++rt)
          az[rt][ct] = __builtin_amdgcn_mfma_f32_16x16x32_f16(a_[rt], b_, az[rt][ct], 0, 0, 0);
      }
    }
#pragma unroll
    for (int rt = 0; rt < 4; ++rt)
#pragma unroll
      for (int ct = 0; ct < 4; ++ct)
#pragma unroll
        for (int i = 0; i < 4; ++i) {
          float sg = 1.f / (1.f + __expf(-az[rt][ct][i]));
          rz[(rt * 16 + kh * 4 + i) * 264 + wv * 64 + ct * 16 + cl] = (f16)sg;
        }
  }
  __syncthreads();
  // ---- G_ni, G_nh: standard 2x2 over [64][128] each ----
  f32x4 ai_[2][4], ah_[2][4];
#pragma unroll
  for (int ct = 0; ct < 4; ++ct) {
    float bi = bih[256 + wc * 64 + ct * 16 + cl];
    float bh = bhh[256 + wc * 64 + ct * 16 + cl];
    ai_[0][ct] = (f32x4){bi, bi, bi, bi}; ai_[1][ct] = ai_[0][ct];
    ah_[0][ct] = (f32x4){bh, bh, bh, bh}; ah_[1][ct] = ah_[0][ct];
  }
#pragma unroll
  for (int kc = 0; kc < 4; ++kc) {
    f16x8 a0 = *(const f16x8*)&ac[(wr * 32 + cl) * 264 + kc * 32 + kh * 8];
    f16x8 a1 = *(const f16x8*)&ac[(wr * 32 + 16 + cl) * 264 + kc * 32 + kh * 8];
    f16x8 p0 = *(const f16x8*)&ac[(wr * 32 + cl) * 264 + 128 + kc * 32 + kh * 8];
    f16x8 p1 = *(const f16x8*)&ac[(wr * 32 + 16 + cl) * 264 + 128 + kc * 32 + kh * 8];
#pragma unroll
    for (int ct = 0; ct < 4; ++ct) {
      f16x8 bi_ = *(const f16x8*)&wg[(size_t)(((128 + kc * 8 + wc * 4 + ct)) * 64 + lane) * 8];
      f16x8 bh_ = *(const f16x8*)&wg[(size_t)(((160 + kc * 8 + wc * 4 + ct)) * 64 + lane) * 8];
      ai_[0][ct] = __builtin_amdgcn_mfma_f32_16x16x32_f16(a0, bi_, ai_[0][ct], 0, 0, 0);
      ai_[1][ct] = __builtin_amdgcn_mfma_f32_16x16x32_f16(a1, bi_, ai_[1][ct], 0, 0, 0);
      ah_[0][ct] = __builtin_amdgcn_mfma_f32_16x16x32_f16(p0, bh_, ah_[0][ct], 0, 0, 0);
      ah_[1][ct] = __builtin_amdgcn_mfma_f32_16x16x32_f16(p1, bh_, ah_[1][ct], 0, 0, 0);
    }
  }
  // ---- epilogue: n = tanh(i_n + r*h_n); out = (1-z)n + z*hp ----
#pragma unroll
  for (int rt = 0; rt < 2; ++rt)
#pragma unroll
    for (int ct = 0; ct < 4; ++ct)
#pragma unroll
      for (int i = 0; i < 4; ++i) {
        int row = wr * 32 + rt * 16 + kh * 4 + i;
        int col = wc * 64 + ct * 16 + cl;
        int grow = r0 + row;
        if (grow < NN) {
          float r_ = (float)rz[row * 264 + col];
          float z_ = (float)rz[row * 264 + 128 + col];
          float n_ = tanhf(ai_[rt][ct][i] + r_ * ah_[rt][ct][i]);
          float hpv = (float)ac[row * 264 + 128 + col];
          out[(size_t)grow * 128 + col] = (1.f - z_) * n_ + z_ * hpv;
        }
      }
}

// ============================================================================
// Transposed-D MFMA machinery (update kernel)
// ============================================================================
#define MFMA_T(APTR, ASTR, ASWZ, NKC, UNIT0, BIAS)                             \
  {                                                                            \
    _Pragma("unroll") for (int nt = 0; nt < 2; ++nt) {                         \
      f32x4 bv_ = *(const f32x4*)((BIAS) + wv * 32 + nt * 16 + kh * 4);        \
      _Pragma("unroll") for (int et = 0; et < 4; ++et) acc[nt][et] = bv_;      \
    }                                                                          \
    _Pragma("unroll 2") for (int kc = 0; kc < (NKC); ++kc) {                   \
      f16x8 wfr_[2];                                                           \
      _Pragma("unroll") for (int nt = 0; nt < 2; ++nt)                         \
        wfr_[nt] = *(const f16x8*)&wp[(size_t)(((UNIT0) + kc * 8 + wv * 2 + nt) * 64 + lane) * 8]; \
      _Pragma("unroll") for (int et = 0; et < 4; ++et) {                       \
        int r_ = et * 16 + cl;                                                 \
        int idx_ = r_ * (ASTR) + kc * 32 + kh * 8;                             \
        if (ASWZ) idx_ ^= ((r_ & 7) << 3);                                     \
        f16x8 efr_ = *(const f16x8*)&(APTR)[idx_];                             \
        _Pragma("unroll") for (int nt = 0; nt < 2; ++nt)                       \
          acc[nt][et] = __builtin_amdgcn_mfma_f32_16x16x32_f16(wfr_[nt], efr_, acc[nt][et], 0, 0, 0); \
      }                                                                        \
    }                                                                          \
  }

#define STORE_T(DPTR, RELU)                                                    \
  _Pragma("unroll") for (int nt = 0; nt < 2; ++nt)                             \
    _Pragma("unroll") for (int et = 0; et < 4; ++et) {                         \
      float v0_ = acc[nt][et][0], v1_ = acc[nt][et][1],                        \
            v2_ = acc[nt][et][2], v3_ = acc[nt][et][3];                        \
      if (RELU) { v0_ = fmaxf(v0_, 0.f); v1_ = fmaxf(v1_, 0.f);                \
                  v2_ = fmaxf(v2_, 0.f); v3_ = fmaxf(v3_, 0.f); }              \
      int r_ = et * 16 + cl;                                                   \
      int idx_ = (r_ * 128 + wv * 32 + nt * 16 + kh * 4) ^ ((r_ & 7) << 3);    \
      *(f16x4*)&(DPTR)[idx_] = (f16x4){(f16)v0_, (f16)v1_, (f16)v2_, (f16)v3_};\
    }

// ============================================================================
// update: h' = LN(h + MLP2([h|aggr]))
// ============================================================================
__global__ __launch_bounds__(256, 2)
void update_mfma_kernel(const f16* __restrict__ h16, const float* __restrict__ aggr,
                        const f16* __restrict__ wp,
                        const float* __restrict__ b1, const float* __restrict__ b2,
                        const float* __restrict__ lng, const float* __restrict__ lnb,
                        f16* __restrict__ h16out) {
  __shared__ f16 ua[64 * 264];
  __shared__ f16 tb[64 * 128];
  __shared__ f16 emb[64 * 128];
  const int tid = threadIdx.x;
  const int lane = tid & 63;
  const int wv = tid >> 6;
  const int cl = lane & 15;
  const int kh = lane >> 4;
  const int r0 = blockIdx.x * 64;
#pragma unroll
  for (int it = 0; it < 8; ++it) {
    int f = tid + it * 256;
    int row = f >> 5, c8 = f & 31;
    int grow = r0 + row;
    f16x8 v = {};
    if (grow < NN) {
      if (c8 < 16) {
        v = *(const f16x8*)(h16 + (size_t)grow * 128 + c8 * 8);
      } else {
        const float* sp = aggr + (size_t)grow * 128 + (c8 - 16) * 8;
        float4 u0 = *(const float4*)sp, u1 = *(const float4*)(sp + 4);
        v = (f16x8){(f16)u0.x, (f16)u0.y, (f16)u0.z, (f16)u0.w,
                    (f16)u1.x, (f16)u1.y, (f16)u1.z, (f16)u1.w};
      }
    }
    *(f16x8*)&ua[row * 264 + c8 * 8] = v;
  }
  __syncthreads();
  f32x4 acc[2][4];
  MFMA_T(ua, 264, 0, 8, 0, b1);
  STORE_T(tb, 1);
  __syncthreads();
  MFMA_T(tb, 128, 1, 4, 64, b2);
  STORE_T(emb, 0);
  __syncthreads();
  {
    const int row = tid >> 2, q = tid & 3;
    const int grow = r0 + row;
    float y[32];
    float s = 0.f, ss = 0.f;
#pragma unroll
    for (int j = 0; j < 4; ++j) {
      int col = q * 32 + j * 8;
      int ei = (row * 128 + col) ^ ((row & 7) << 3);
      f16x8 ev = *(const f16x8*)&emb[ei];
      f16x8 rv = *(const f16x8*)&ua[row * 264 + col];
#pragma unroll
      for (int e = 0; e < 8; ++e) {
        float t = (float)ev[e] + (float)rv[e];
        y[j * 8 + e] = t; s += t; ss += t * t;
      }
    }
    s += __shfl_xor(s, 1);  s += __shfl_xor(s, 2);
    ss += __shfl_xor(ss, 1); ss += __shfl_xor(ss, 2);
    float mean = s * (1.f / 128.f);
    float var = ss * (1.f / 128.f) - mean * mean;
    float rstd = rsqrtf(var + 1e-5f);
    if (grow < NN) {
#pragma unroll
      for (int j = 0; j < 4; ++j) {
        int col = q * 32 + j * 8;
        const float4 g0 = *(const float4*)(lng + col), g1 = *(const float4*)(lng + col + 4);
        const float4 q0 = *(const float4*)(lnb + col), q1 = *(const float4*)(lnb + col + 4);
        float gv[8] = {g0.x, g0.y, g0.z, g0.w, g1.x, g1.y, g1.z, g1.w};
        float bv[8] = {q0.x, q0.y, q0.z, q0.w, q1.x, q1.y, q1.z, q1.w};
        f16x8 o;
#pragma unroll
        for (int e = 0; e < 8; ++e)
          o[e] = (f16)((y[j * 8 + e] - mean) * rstd * gv[e] + bv[e]);
        *(f16x8*)(h16out + (size_t)grow * 128 + col) = o;
      }
    }
  }
}

// ---------------- launch ----------------
extern "C" void kernel_launch(void* const* d_in, const int* in_sizes, int n_in,
                              void* d_out, int out_size, void* d_ws, size_t ws_size,
                              hipStream_t stream) {
  (void)in_sizes; (void)n_in; (void)out_size; (void)ws_size;
  const float* x         = (const float*)d_in[0];
  const float* edge_attr = (const float*)d_in[1];
  const float* h_prev    = (const float*)d_in[2];
  const float* enc_w1    = (const float*)d_in[3];
  const float* enc_b1    = (const float*)d_in[4];
  const float* enc_w2    = (const float*)d_in[5];
  const float* enc_b2    = (const float*)d_in[6];
  const float* et_w1     = (const float*)d_in[7];
  const float* et_b1     = (const float*)d_in[8];
  const float* et_w2     = (const float*)d_in[9];
  const float* et_b2     = (const float*)d_in[10];
  const float* msg_w1    = (const float*)d_in[11];
  const float* msg_b1    = (const float*)d_in[12];
  const float* msg_w2    = (const float*)d_in[13];
  const float* msg_b2    = (const float*)d_in[14];
  const float* upd_w1    = (const float*)d_in[15];
  const float* upd_b1    = (const float*)d_in[16];
  const float* upd_w2    = (const float*)d_in[17];
  const float* upd_b2    = (const float*)d_in[18];
  const float* ln_g      = (const float*)d_in[19];
  const float* ln_b      = (const float*)d_in[20];
  const float* gru_wih   = (const float*)d_in[21];
  const float* gru_whh   = (const float*)d_in[22];
  const float* gru_bih   = (const float*)d_in[23];
  const float* gru_bhh   = (const float*)d_in[24];
  const int* edge_index  = (const int*)d_in[25];
  const int* esrc = edge_index;
  const int* edst = edge_index + NE;

  // workspace layout (same footprint as R7)
  float* ws    = (float*)d_ws;
  float* aggrf = ws;                                 // N*128 f32
  float* wreg  = ws + (size_t)NN * 128;              // old wihT/whhT region: 98304 f32
  f16*   wg    = (f16*)wreg;                         // 192*512 f16 (= 49152 f32)
  float* brz   = wreg + 49152;                       // 256 f32
  f16*   wpenc = (f16*)(brz + 256);                  // 64*512 f16 (= 16384 f32)
  f16*   h16a  = (f16*)(wreg + 98304);               // N*128 f16
  f16*   h16b  = h16a + (size_t)NN * 128;            // N*128 f16
  f16*   wpe   = h16b + (size_t)NN * 128;            // 4*168*512 f16
  f16*   wpu   = wpe + 4 * 86016;                    // 4*96*512 f16
  f16*   ea16p = wpu + 4 * 96 * 512;                 // E*32 f16 (dst-sorted)

  // d_out scratch (consumed before gru writes d_out at the end)
  int* iout   = (int*)d_out;
  int* deg    = iout;                   // NN
  int* offs   = iout + 51200;           // NN+1
  int* cursor = iout + 102400;          // NN
  int* eord   = iout + 153600;          // NE
  int* dstp   = iout + 153600 + NE;     // NE
  int* esp    = iout + 153600 + 2 * NE; // NE (ends 2,553,600 ints)
  f16* x16    = (f16*)(iout + 2600000); // N*128 f16 (ends 5,800,000 ints < 6.4M)

  // ---- CSR build ----
  hipMemsetAsync(deg, 0, NN * sizeof(int), stream);
  hist_kernel<<<(NE + 255) / 256, 256, 0, stream>>>(edst, deg);
  scan_kernel<<<1, 256, 0, stream>>>(deg, offs, NN);
  copy_cursor_kernel<<<(NN + 255) / 256, 256, 0, stream>>>(offs, cursor);
  fill_kernel<<<(NE + 255) / 256, 256, 0, stream>>>(edst, cursor, eord);
  permute_kernel<<<(NE + 255) / 256, 256, 0, stream>>>(eord, esrc, edst, edge_attr,
                                                       dstp, esp, ea16p);

  // ---- weight packs / input cvt / encoder ----
  pack_w_kernel<<<(4 * 86016 + 255) / 256, 256, 0, stream>>>(et_w1, et_w2, msg_w1, msg_w2, wpe);
  pack_upd_kernel<<<(4 * 96 * 512 + 255) / 256, 256, 0, stream>>>(upd_w1, upd_w2, wpu);
  pack_gru_kernel<<<(192 * 512 + 255) / 256, 256, 0, stream>>>(gru_wih, gru_whh,
                                                               gru_bih, gru_bhh, wg, brz);
  pack_enc_kernel<<<(64 * 512 + 255) / 256, 256, 0, stream>>>(enc_w1, enc_w2, wpenc);
  cvt_x_kernel<<<(NN * 16 + 255) / 256, 256, 0, stream>>>(x, x16);
  encoder_mfma_kernel<<<(NN + 63) / 64, 256, 0, stream>>>(x16, wpenc, enc_b1, enc_b2, h16a);

  f16* hc = h16a;
  f16* hn = h16b;
  for (int l = 0; l < 4; ++l) {
    hipMemsetAsync(aggrf, 0, (size_t)NN * 128 * sizeof(float), stream);
    edge_mfma_kernel<<<NE / 64, 256, 0, stream>>>(
        hc, ea16p, esp, dstp,
        wpe + (size_t)l * 86016,
        et_b1 + l * 128, et_b2 + l * 128,
        msg_b1 + l * 128, msg_b2 + l * 128,
        aggrf);
    update_mfma_kernel<<<(NN + 63) / 64, 256, 0, stream>>>(
        hc, aggrf,
        wpu + (size_t)l * 96 * 512,
        upd_b1 + l * 128, upd_b2 + l * 128,
        ln_g, ln_b, hn);
    f16* t = hc; hc = hn; hn = t;
  }
  // after 4 swaps: hc == h16a
  gru_mfma_kernel<<<(NN + 63) / 64, 256, 0, stream>>>(hc, h_prev, wg, brz,
                                                      gru_bih, gru_bhh, (float*)d_out);
}

// Round 9
// 1160.253 us; speedup vs baseline: 1.9724x; 1.0853x over previous
//
#include <hip/hip_runtime.h>
#include <hip/hip_bf16.h>
#include <cstdint>

#define NN 50000
#define NE 800000

typedef _Float16 f16;
typedef f16 f16x8 __attribute__((ext_vector_type(8)));
typedef f16 f16x4 __attribute__((ext_vector_type(4)));
typedef float f32x4 __attribute__((ext_vector_type(4)));

#define TB_STR 136   // f16 stride for [64][128] intermediate (272B)

// ============================================================================
// CSR build: dst-sorted edge permutation (rebuilt every call; graph-safe)
// ============================================================================
__global__ void hist_kernel(const int* __restrict__ edst, int* __restrict__ deg) {
  int e = blockIdx.x * 256 + threadIdx.x;
  if (e < NE) atomicAdd(&deg[edst[e]], 1);
}

__global__ void scan_kernel(const int* __restrict__ deg, int* __restrict__ offs, int n) {
  __shared__ int tmp[256];
  __shared__ int carry;
  const int tid = threadIdx.x;
  if (tid == 0) carry = 0;
  __syncthreads();
  for (int base = 0; base < n; base += 1024) {
    int v[4]; int s = 0;
#pragma unroll
    for (int j = 0; j < 4; ++j) {
      int idx = base + tid * 4 + j;
      v[j] = (idx < n) ? deg[idx] : 0;
      s += v[j];
    }
    tmp[tid] = s;
    __syncthreads();
    for (int ofs = 1; ofs < 256; ofs <<= 1) {
      int t = (tid >= ofs) ? tmp[tid - ofs] : 0;
      __syncthreads();
      tmp[tid] += t;
      __syncthreads();
    }
    int excl = carry + tmp[tid] - s;
#pragma unroll
    for (int j = 0; j < 4; ++j) {
      int idx = base + tid * 4 + j;
      if (idx < n) offs[idx] = excl;
      excl += v[j];
    }
    __syncthreads();
    if (tid == 255) carry += tmp[255];
    __syncthreads();
  }
  if (tid == 0) offs[n] = carry;
}

__global__ void copy_cursor_kernel(const int* __restrict__ offs, int* __restrict__ cursor) {
  int i = blockIdx.x * 256 + threadIdx.x;
  if (i < NN) cursor[i] = offs[i];
}

__global__ void fill_kernel(const int* __restrict__ edst, int* __restrict__ cursor,
                            int* __restrict__ eord) {
  int e = blockIdx.x * 256 + threadIdx.x;
  if (e < NE) {
    int p = atomicAdd(&cursor[edst[e]], 1);
    eord[p] = e;
  }
}

__global__ void permute_kernel(const int* __restrict__ eord,
                               const int* __restrict__ esrc,
                               const int* __restrict__ edst,
                               const float* __restrict__ ea,
                               int* __restrict__ dstp, int* __restrict__ esp,
                               f16* __restrict__ ea16p) {
  int i = blockIdx.x * 256 + threadIdx.x;
  if (i >= NE) return;
  int e = eord[i];
  dstp[i] = edst[e];
  esp[i] = esrc[e];
  const float* sp = ea + (size_t)e * 32;
  f16* dp = ea16p + (size_t)i * 32;
#pragma unroll
  for (int j = 0; j < 4; ++j) {
    float4 u0 = *(const float4*)(sp + j * 8), u1 = *(const float4*)(sp + j * 8 + 4);
    f16x8 v = {(f16)u0.x, (f16)u0.y, (f16)u0.z, (f16)u0.w,
               (f16)u1.x, (f16)u1.y, (f16)u1.z, (f16)u1.w};
    *(f16x8*)(dp + j * 8) = v;
  }
}

// ============================================================================
// W23 fusion: W23[l] = et_w2[l] @ msg_w1[l]  (f32);
// b23[l][n] = sum_m et_b2[l][m]*msg_w1[l][m][n] + msg_b1[l][n]
// grid: 4 layers x 8 col-chunks of 16
// ============================================================================
__global__ void w23_kernel(const float* __restrict__ et_w2,
                           const float* __restrict__ et_b2,
                           const float* __restrict__ msg_w1,
                           const float* __restrict__ msg_b1,
                           float* __restrict__ w23, float* __restrict__ b23) {
  const int l = blockIdx.x >> 3, cc = blockIdx.x & 7;
  const float* W2 = et_w2 + (size_t)l * 16384;
  const float* W3 = msg_w1 + (size_t)l * 16384;
  __shared__ float w3s[128][17];
  const int tid = threadIdx.x;
#pragma unroll
  for (int it = 0; it < 8; ++it) {
    int f = tid + it * 256;
    int m = f >> 4, n = f & 15;
    w3s[m][n] = W3[m * 128 + cc * 16 + n];
  }
  __syncthreads();
  const int k = tid >> 1, nh = (tid & 1) * 8;
  float s[8] = {};
  for (int m = 0; m < 128; ++m) {
    float w2v = W2[k * 128 + m];
#pragma unroll
    for (int j = 0; j < 8; ++j) s[j] = fmaf(w2v, w3s[m][nh + j], s[j]);
  }
#pragma unroll
  for (int j = 0; j < 8; ++j)
    w23[(size_t)l * 16384 + k * 128 + cc * 16 + nh + j] = s[j];
  if (k == 0) {
    float sb[8] = {};
    for (int m = 0; m < 128; ++m) {
      float b2v = et_b2[l * 128 + m];
#pragma unroll
      for (int j = 0; j < 8; ++j) sb[j] = fmaf(b2v, w3s[m][nh + j], sb[j]);
    }
#pragma unroll
    for (int j = 0; j < 8; ++j)
      b23[l * 128 + cc * 16 + nh + j] = sb[j] + msg_b1[l * 128 + cc * 16 + nh + j];
  }
}

// ============================================================================
// Weight pre-pack (f16 MFMA fragment layout).
// unit = kc*8 + ct ; element [lane][i] = W[kc*32 + (lane>>4)*8 + i][ct*16 + (lane&15)]
// Edge pack per layer (POST-FUSION): et_w1 72 | W23 32 | msg_w2 32 = 136 units
// ============================================================================
__global__ void pack_w_kernel(const float* __restrict__ et_w1,
                              const float* __restrict__ w23,
                              const float* __restrict__ msg_w2,
                              f16* __restrict__ wpack) {
  int idx = blockIdx.x * 256 + threadIdx.x;
  if (idx >= 4 * 69632) return;
  int l = idx / 69632;
  int rem = idx - l * 69632;
  int unit = rem >> 9;
  int e = rem & 511;
  int ln = e >> 3, i = e & 7;
  const float* src;
  int ul;
  if (unit < 72)       { src = et_w1  + (size_t)l * 288 * 128; ul = unit; }
  else if (unit < 104) { src = w23    + (size_t)l * 16384;     ul = unit - 72; }
  else                 { src = msg_w2 + (size_t)l * 16384;     ul = unit - 104; }
  int kc = ul >> 3, ct = ul & 7;
  int k = kc * 32 + (ln >> 4) * 8 + i;
  int col = ct * 16 + (ln & 15);
  wpack[idx] = (f16)src[k * 128 + col];
}

__global__ void pack_upd_kernel(const float* __restrict__ upd_w1,
                                const float* __restrict__ upd_w2,
                                f16* __restrict__ wpu) {
  int idx = blockIdx.x * 256 + threadIdx.x;
  if (idx >= 4 * 96 * 512) return;
  int l = idx / (96 * 512);
  int rem = idx - l * (96 * 512);
  int unit = rem >> 9, e = rem & 511, ln = e >> 3, i = e & 7;
  const float* src;
  int ul;
  if (unit < 64) { src = upd_w1 + (size_t)l * 256 * 128; ul = unit; }
  else           { src = upd_w2 + (size_t)l * 128 * 128; ul = unit - 64; }
  int kc = ul >> 3, ct = ul & 7;
  int k = kc * 32 + (ln >> 4) * 8 + i;
  int col = ct * 16 + (ln & 15);
  wpu[idx] = (f16)src[k * 128 + col];
}

// GRU pack: units 0..127 = W_rz (K=256 over [h|hp], N=256, torch W^T);
// 128..159 = W_ni; 160..191 = W_nh. brz[j] = bih[j]+bhh[j] for j<256.
__global__ void pack_gru_kernel(const float* __restrict__ wih,
                                const float* __restrict__ whh,
                                const float* __restrict__ bih,
                                const float* __restrict__ bhh,
                                f16* __restrict__ wg, float* __restrict__ brz) {
  int idx = blockIdx.x * 256 + threadIdx.x;
  if (idx < 256) brz[idx] = bih[idx] + bhh[idx];
  if (idx >= 192 * 512) return;
  int unit = idx >> 9, e = idx & 511, ln = e >> 3, i = e & 7;
  int krow = (ln >> 4) * 8 + i;
  int cl16 = ln & 15;
  f16 val;
  if (unit < 128) {
    int kc = unit >> 4, ctg = unit & 15;
    int k = kc * 32 + krow;
    int col = ctg * 16 + cl16;
    float w = (k < 128) ? wih[col * 128 + k] : whh[col * 128 + (k - 128)];
    val = (f16)w;
  } else if (unit < 160) {
    int ul = unit - 128;
    int k = (ul >> 3) * 32 + krow;
    int col = (ul & 7) * 16 + cl16;
    val = (f16)wih[(256 + col) * 128 + k];
  } else {
    int ul = unit - 160;
    int k = (ul >> 3) * 32 + krow;
    int col = (ul & 7) * 16 + cl16;
    val = (f16)whh[(256 + col) * 128 + k];
  }
  wg[idx] = val;
}

__global__ void pack_enc_kernel(const float* __restrict__ w1,
                                const float* __restrict__ w2,
                                f16* __restrict__ wpenc) {
  int idx = blockIdx.x * 256 + threadIdx.x;
  if (idx >= 64 * 512) return;
  int unit = idx >> 9, e = idx & 511, ln = e >> 3, i = e & 7;
  const float* src = (unit < 32) ? w1 : w2;
  int ul = unit & 31;
  int k = (ul >> 3) * 32 + (ln >> 4) * 8 + i;
  int col = (ul & 7) * 16 + (ln & 15);
  wpenc[idx] = (f16)src[k * 128 + col];
}

__global__ void cvt_x_kernel(const float* __restrict__ x, f16* __restrict__ x16) {
  int idx = blockIdx.x * 256 + threadIdx.x;
  if (idx >= NN * 16) return;
  const float* sp = x + (size_t)idx * 8;
  float4 u0 = *(const float4*)sp, u1 = *(const float4*)(sp + 4);
  f16x8 v = {(f16)u0.x, (f16)u0.y, (f16)u0.z, (f16)u0.w,
             (f16)u1.x, (f16)u1.y, (f16)u1.z, (f16)u1.w};
  *(f16x8*)(x16 + (size_t)idx * 8) = v;
}

// ============================================================================
// Shared MFMA tile macros (D-normal). Wave (wr,wc): rows wr*32..+32,
// cols wc*64..+64. acc[rt][ct]. C/D: lane -> col=ct*16+cl, rows rt*16+kh*4+{0..3}.
// ============================================================================
#define EDGE_ACC_INIT(BIAS)                                                    \
  _Pragma("unroll") for (int ct = 0; ct < 4; ++ct) {                           \
    float bv_ = (BIAS)[wc * 64 + ct * 16 + cl];                                \
    acc[0][ct] = (f32x4){bv_, bv_, bv_, bv_};                                  \
    acc[1][ct] = acc[0][ct];                                                   \
  }

#define EDGE_MFMA_KC(A0, A1, UNIT)                                             \
  _Pragma("unroll") for (int ct = 0; ct < 4; ++ct) {                           \
    f16x8 b_ = *(const f16x8*)&wp[(size_t)(((UNIT) + wc * 4 + ct) * 64 + lane) * 8]; \
    acc[0][ct] = __builtin_amdgcn_mfma_f32_16x16x32_f16(A0, b_, acc[0][ct], 0, 0, 0); \
    acc[1][ct] = __builtin_amdgcn_mfma_f32_16x16x32_f16(A1, b_, acc[1][ct], 0, 0, 0); \
  }

#define EDGE_GEMM_LDS(APTR, UNIT0, BIAS)                                       \
  {                                                                            \
    EDGE_ACC_INIT(BIAS);                                                       \
    _Pragma("unroll") for (int kc = 0; kc < 4; ++kc) {                         \
      f16x8 a0_ = *(const f16x8*)&(APTR)[(wr * 32 + cl) * TB_STR + kc * 32 + kh * 8]; \
      f16x8 a1_ = *(const f16x8*)&(APTR)[(wr * 32 + 16 + cl) * TB_STR + kc * 32 + kh * 8]; \
      EDGE_MFMA_KC(a0_, a1_, (UNIT0) + kc * 8);                                \
    }                                                                          \
  }

#define EDGE_STORE(DST, RELU)                                                  \
  _Pragma("unroll") for (int rt = 0; rt < 2; ++rt)                             \
    _Pragma("unroll") for (int ct = 0; ct < 4; ++ct)                           \
      _Pragma("unroll") for (int i = 0; i < 4; ++i) {                          \
        float v_ = acc[rt][ct][i];                                             \
        if (RELU) v_ = fmaxf(v_, 0.f);                                         \
        (DST)[(wr * 32 + rt * 16 + kh * 4 + i) * TB_STR + wc * 64 + ct * 16 + cl] = (f16)v_; \
      }

// ============================================================================
// Edge kernel (dst-sorted, W23-fused: 3 GEMMs) + run-reduction scatter
// ============================================================================
__global__ __launch_bounds__(256, 6)
void edge_mfma_kernel(const f16* __restrict__ h16, const f16* __restrict__ ea16p,
                      const int* __restrict__ esp, const int* __restrict__ dstp,
                      const f16* __restrict__ wp,
                      const float* __restrict__ b1, const float* __restrict__ b23,
                      const float* __restrict__ b4,
                      float* __restrict__ aggrf) {
  __shared__ f16 buf[64 * TB_STR];
  __shared__ int eidx[128];
  const int tid = threadIdx.x;
  const int lane = tid & 63;
  const int wv = tid >> 6;
  const int wr = wv >> 1, wc = wv & 1;
  const int cl = lane & 15;
  const int kh = lane >> 4;
  const int e0 = blockIdx.x * 64;
  if (tid < 64) eidx[tid] = dstp[e0 + tid];
  else if (tid < 128) eidx[tid] = esp[e0 + tid - 64];
  __syncthreads();

  const int r0 = wr * 32 + cl, r1 = r0 + 16;
  const f16* pd0 = h16 + (size_t)eidx[r0] * 128 + kh * 8;
  const f16* pd1 = h16 + (size_t)eidx[r1] * 128 + kh * 8;
  const f16* ps0 = h16 + (size_t)eidx[64 + r0] * 128 + kh * 8;
  const f16* ps1 = h16 + (size_t)eidx[64 + r1] * 128 + kh * 8;
  const f16* pe0 = ea16p + (size_t)(e0 + r0) * 32 + kh * 8;
  const f16* pe1 = ea16p + (size_t)(e0 + r1) * 32 + kh * 8;

  f32x4 acc[2][4];
  // ---- GEMM1: t1 = relu(e_in@W1+b1), K=288, A direct from global ----
  EDGE_ACC_INIT(b1);
#pragma unroll
  for (int kc = 0; kc < 4; ++kc) {
    f16x8 a0_ = *(const f16x8*)(pd0 + kc * 32);
    f16x8 a1_ = *(const f16x8*)(pd1 + kc * 32);
    EDGE_MFMA_KC(a0_, a1_, kc * 8);
  }
#pragma unroll
  for (int kc = 4; kc < 8; ++kc) {
    f16x8 a0_ = *(const f16x8*)(ps0 + (kc - 4) * 32);
    f16x8 a1_ = *(const f16x8*)(ps1 + (kc - 4) * 32);
    EDGE_MFMA_KC(a0_, a1_, kc * 8);
  }
  {
    f16x8 a0_ = *(const f16x8*)pe0;
    f16x8 a1_ = *(const f16x8*)pe1;
    EDGE_MFMA_KC(a0_, a1_, 64);
  }
  EDGE_STORE(buf, 1);
  __syncthreads();
  // ---- GEMM2' (fused W2@W3): msg_hidden = relu(t1@W23 + b23), K=128 ----
  EDGE_GEMM_LDS(buf, 72, b23);
  __syncthreads();
  EDGE_STORE(buf, 1);
  __syncthreads();
  // ---- GEMM3': msg = msg_hidden@W4 + b4, K=128 ----
  EDGE_GEMM_LDS(buf, 104, b4);
  __syncthreads();
  EDGE_STORE(buf, 0);
  __syncthreads();
  // ---- run-reduction scatter over sorted dst ----
  {
    const int c = tid & 127;
    const int rbeg = (tid >> 7) * 32;
    float sum = 0.f;
    int cur = eidx[rbeg];
    bool openL = true;
    for (int r = rbeg; r < rbeg + 32; ++r) {
      sum += (float)buf[r * TB_STR + c];
      bool last = (r == rbeg + 31);
      int nxt = last ? -1 : eidx[r + 1];
      if (last || nxt != cur) {
        float* ap = aggrf + (size_t)cur * 128 + c;
        if (openL || last) unsafeAtomicAdd(ap, sum);
        else *ap = sum;
        sum = 0.f; cur = nxt; openL = false;
      }
    }
  }
}

// ============================================================================
// encoder: h16 = f16(relu(x16@W1+b1)@W2+b2)  -- f16 MFMA
// ============================================================================
__global__ __launch_bounds__(256, 4)
void encoder_mfma_kernel(const f16* __restrict__ x16, const f16* __restrict__ wp,
                         const float* __restrict__ b1, const float* __restrict__ b2,
                         f16* __restrict__ h16out) {
  __shared__ f16 buf[64 * TB_STR];
  const int tid = threadIdx.x;
  const int lane = tid & 63;
  const int wv = tid >> 6;
  const int wr = wv >> 1, wc = wv & 1;
  const int cl = lane & 15;
  const int kh = lane >> 4;
  const int r0 = blockIdx.x * 64;
  const int gr0 = min(r0 + wr * 32 + cl, NN - 1);
  const int gr1 = min(r0 + wr * 32 + 16 + cl, NN - 1);
  const f16* px0 = x16 + (size_t)gr0 * 128 + kh * 8;
  const f16* px1 = x16 + (size_t)gr1 * 128 + kh * 8;
  f32x4 acc[2][4];
  EDGE_ACC_INIT(b1);
#pragma unroll
  for (int kc = 0; kc < 4; ++kc) {
    f16x8 a0_ = *(const f16x8*)(px0 + kc * 32);
    f16x8 a1_ = *(const f16x8*)(px1 + kc * 32);
    EDGE_MFMA_KC(a0_, a1_, kc * 8);
  }
  EDGE_STORE(buf, 1);
  __syncthreads();
  EDGE_GEMM_LDS(buf, 32, b2);
  __syncthreads();
  EDGE_STORE(buf, 0);
  __syncthreads();
#pragma unroll
  for (int it = 0; it < 4; ++it) {
    int f = tid + it * 256;
    int row = f >> 4, c8 = f & 15;
    int grow = r0 + row;
    if (grow < NN) {
      f16x8 v = *(const f16x8*)&buf[row * TB_STR + c8 * 8];
      *(f16x8*)(h16out + (size_t)grow * 128 + c8 * 8) = v;
    }
  }
}

// ============================================================================
// GRU cell, f16 MFMA (R8, unchanged)
// ============================================================================
__global__ __launch_bounds__(256, 2)
void gru_mfma_kernel(const f16* __restrict__ h16, const float* __restrict__ hprev,
                     const f16* __restrict__ wg, const float* __restrict__ brz,
                     const float* __restrict__ bih, const float* __restrict__ bhh,
                     float* __restrict__ out) {
  __shared__ f16 ac[64 * 264];
  __shared__ f16 rz[64 * 264];
  const int tid = threadIdx.x;
  const int lane = tid & 63;
  const int wv = tid >> 6;
  const int wr = wv >> 1, wc = wv & 1;
  const int cl = lane & 15;
  const int kh = lane >> 4;
  const int r0 = blockIdx.x * 64;
#pragma unroll
  for (int it = 0; it < 8; ++it) {
    int f = tid + it * 256;
    int row = f >> 5, c8 = f & 31;
    int grow = r0 + row;
    f16x8 v = {};
    if (grow < NN) {
      if (c8 < 16) {
        v = *(const f16x8*)(h16 + (size_t)grow * 128 + c8 * 8);
      } else {
        const float* sp = hprev + (size_t)grow * 128 + (c8 - 16) * 8;
        float4 u0 = *(const float4*)sp, u1 = *(const float4*)(sp + 4);
        v = (f16x8){(f16)u0.x, (f16)u0.y, (f16)u0.z, (f16)u0.w,
                    (f16)u1.x, (f16)u1.y, (f16)u1.z, (f16)u1.w};
      }
    }
    *(f16x8*)&ac[row * 264 + c8 * 8] = v;
  }
  __syncthreads();
  {
    f32x4 az[4][4];
#pragma unroll
    for (int ct = 0; ct < 4; ++ct) {
      float bv = brz[wv * 64 + ct * 16 + cl];
#pragma unroll
      for (int rt = 0; rt < 4; ++rt) az[rt][ct] = (f32x4){bv, bv, bv, bv};
    }
#pragma unroll
    for (int kc = 0; kc < 8; ++kc) {
      f16x8 a_[4];
#pragma unroll
      for (int rt = 0; rt < 4; ++rt)
        a_[rt] = *(const f16x8*)&ac[(rt * 16 + cl) * 264 + kc * 32 + kh * 8];
#pragma unroll
      for (int ct = 0; ct < 4; ++ct) {
        f16x8 b_ = *(const f16x8*)&wg[(size_t)((kc * 16 + wv * 4 + ct) * 64 + lane) * 8];
#pragma unroll
        for (int rt = 0; rt < 4; ++rt)
          az[rt][ct] = __builtin_amdgcn_mfma_f32_16x16x32_f16(a_[rt], b_, az[rt][ct], 0, 0, 0);
      }
    }
#pragma unroll
    for (int rt = 0; rt < 4; ++rt)
#pragma unroll
      for (int ct = 0; ct < 4; ++ct)
#pragma unroll
        for (int i = 0; i < 4; ++i) {
          float sg = 1.f / (1.f + __expf(-az[rt][ct][i]));
          rz[(rt * 16 + kh * 4 + i) * 264 + wv * 64 + ct * 16 + cl] = (f16)sg;
        }
  }
  __syncthreads();
  f32x4 ai_[2][4], ah_[2][4];
#pragma unroll
  for (int ct = 0; ct < 4; ++ct) {
    float bi = bih[256 + wc * 64 + ct * 16 + cl];
    float bh = bhh[256 + wc * 64 + ct * 16 + cl];
    ai_[0][ct] = (f32x4){bi, bi, bi, bi}; ai_[1][ct] = ai_[0][ct];
    ah_[0][ct] = (f32x4){bh, bh, bh, bh}; ah_[1][ct] = ah_[0][ct];
  }
#pragma unroll
  for (int kc = 0; kc < 4; ++kc) {
    f16x8 a0 = *(const f16x8*)&ac[(wr * 32 + cl) * 264 + kc * 32 + kh * 8];
    f16x8 a1 = *(const f16x8*)&ac[(wr * 32 + 16 + cl) * 264 + kc * 32 + kh * 8];
    f16x8 p0 = *(const f16x8*)&ac[(wr * 32 + cl) * 264 + 128 + kc * 32 + kh * 8];
    f16x8 p1 = *(const f16x8*)&ac[(wr * 32 + 16 + cl) * 264 + 128 + kc * 32 + kh * 8];
#pragma unroll
    for (int ct = 0; ct < 4; ++ct) {
      f16x8 bi_ = *(const f16x8*)&wg[(size_t)(((128 + kc * 8 + wc * 4 + ct)) * 64 + lane) * 8];
      f16x8 bh_ = *(const f16x8*)&wg[(size_t)(((160 + kc * 8 + wc * 4 + ct)) * 64 + lane) * 8];
      ai_[0][ct] = __builtin_amdgcn_mfma_f32_16x16x32_f16(a0, bi_, ai_[0][ct], 0, 0, 0);
      ai_[1][ct] = __builtin_amdgcn_mfma_f32_16x16x32_f16(a1, bi_, ai_[1][ct], 0, 0, 0);
      ah_[0][ct] = __builtin_amdgcn_mfma_f32_16x16x32_f16(p0, bh_, ah_[0][ct], 0, 0, 0);
      ah_[1][ct] = __builtin_amdgcn_mfma_f32_16x16x32_f16(p1, bh_, ah_[1][ct], 0, 0, 0);
    }
  }
#pragma unroll
  for (int rt = 0; rt < 2; ++rt)
#pragma unroll
    for (int ct = 0; ct < 4; ++ct)
#pragma unroll
      for (int i = 0; i < 4; ++i) {
        int row = wr * 32 + rt * 16 + kh * 4 + i;
        int col = wc * 64 + ct * 16 + cl;
        int grow = r0 + row;
        if (grow < NN) {
          float r_ = (float)rz[row * 264 + col];
          float z_ = (float)rz[row * 264 + 128 + col];
          float n_ = tanhf(ai_[rt][ct][i] + r_ * ah_[rt][ct][i]);
          float hpv = (float)ac[row * 264 + 128 + col];
          out[(size_t)grow * 128 + col] = (1.f - z_) * n_ + z_ * hpv;
        }
      }
}

// ============================================================================
// Transposed-D MFMA machinery (update kernel)
// ============================================================================
#define MFMA_T(APTR, ASTR, ASWZ, NKC, UNIT0, BIAS)                             \
  {                                                                            \
    _Pragma("unroll") for (int nt = 0; nt < 2; ++nt) {                         \
      f32x4 bv_ = *(const f32x4*)((BIAS) + wv * 32 + nt * 16 + kh * 4);        \
      _Pragma("unroll") for (int et = 0; et < 4; ++et) acc[nt][et] = bv_;      \
    }                                                                          \
    _Pragma("unroll 2") for (int kc = 0; kc < (NKC); ++kc) {                   \
      f16x8 wfr_[2];                                                           \
      _Pragma("unroll") for (int nt = 0; nt < 2; ++nt)                         \
        wfr_[nt] = *(const f16x8*)&wp[(size_t)(((UNIT0) + kc * 8 + wv * 2 + nt) * 64 + lane) * 8]; \
      _Pragma("unroll") for (int et = 0; et < 4; ++et) {                       \
        int r_ = et * 16 + cl;                                                 \
        int idx_ = r_ * (ASTR) + kc * 32 + kh * 8;                             \
        if (ASWZ) idx_ ^= ((r_ & 7) << 3);                                     \
        f16x8 efr_ = *(const f16x8*)&(APTR)[idx_];                             \
        _Pragma("unroll") for (int nt = 0; nt < 2; ++nt)                       \
          acc[nt][et] = __builtin_amdgcn_mfma_f32_16x16x32_f16(wfr_[nt], efr_, acc[nt][et], 0, 0, 0); \
      }                                                                        \
    }                                                                          \
  }

#define STORE_T(DPTR, RELU)                                                    \
  _Pragma("unroll") for (int nt = 0; nt < 2; ++nt)                             \
    _Pragma("unroll") for (int et = 0; et < 4; ++et) {                         \
      float v0_ = acc[nt][et][0], v1_ = acc[nt][et][1],                        \
            v2_ = acc[nt][et][2], v3_ = acc[nt][et][3];                        \
      if (RELU) { v0_ = fmaxf(v0_, 0.f); v1_ = fmaxf(v1_, 0.f);                \
                  v2_ = fmaxf(v2_, 0.f); v3_ = fmaxf(v3_, 0.f); }              \
      int r_ = et * 16 + cl;                                                   \
      int idx_ = (r_ * 128 + wv * 32 + nt * 16 + kh * 4) ^ ((r_ & 7) << 3);    \
      *(f16x4*)&(DPTR)[idx_] = (f16x4){(f16)v0_, (f16)v1_, (f16)v2_, (f16)v3_};\
    }

// ============================================================================
// update: h' = LN(h + MLP2([h|aggr]))
// ============================================================================
__global__ __launch_bounds__(256, 2)
void update_mfma_kernel(const f16* __restrict__ h16, const float* __restrict__ aggr,
                        const f16* __restrict__ wp,
                        const float* __restrict__ b1, const float* __restrict__ b2,
                        const float* __restrict__ lng, const float* __restrict__ lnb,
                        f16* __restrict__ h16out) {
  __shared__ f16 ua[64 * 264];
  __shared__ f16 tb[64 * 128];
  __shared__ f16 emb[64 * 128];
  const int tid = threadIdx.x;
  const int lane = tid & 63;
  const int wv = tid >> 6;
  const int cl = lane & 15;
  const int kh = lane >> 4;
  const int r0 = blockIdx.x * 64;
#pragma unroll
  for (int it = 0; it < 8; ++it) {
    int f = tid + it * 256;
    int row = f >> 5, c8 = f & 31;
    int grow = r0 + row;
    f16x8 v = {};
    if (grow < NN) {
      if (c8 < 16) {
        v = *(const f16x8*)(h16 + (size_t)grow * 128 + c8 * 8);
      } else {
        const float* sp = aggr + (size_t)grow * 128 + (c8 - 16) * 8;
        float4 u0 = *(const float4*)sp, u1 = *(const float4*)(sp + 4);
        v = (f16x8){(f16)u0.x, (f16)u0.y, (f16)u0.z, (f16)u0.w,
                    (f16)u1.x, (f16)u1.y, (f16)u1.z, (f16)u1.w};
      }
    }
    *(f16x8*)&ua[row * 264 + c8 * 8] = v;
  }
  __syncthreads();
  f32x4 acc[2][4];
  MFMA_T(ua, 264, 0, 8, 0, b1);
  STORE_T(tb, 1);
  __syncthreads();
  MFMA_T(tb, 128, 1, 4, 64, b2);
  STORE_T(emb, 0);
  __syncthreads();
  {
    const int row = tid >> 2, q = tid & 3;
    const int grow = r0 + row;
    float y[32];
    float s = 0.f, ss = 0.f;
#pragma unroll
    for (int j = 0; j < 4; ++j) {
      int col = q * 32 + j * 8;
      int ei = (row * 128 + col) ^ ((row & 7) << 3);
      f16x8 ev = *(const f16x8*)&emb[ei];
      f16x8 rv = *(const f16x8*)&ua[row * 264 + col];
#pragma unroll
      for (int e = 0; e < 8; ++e) {
        float t = (float)ev[e] + (float)rv[e];
        y[j * 8 + e] = t; s += t; ss += t * t;
      }
    }
    s += __shfl_xor(s, 1);  s += __shfl_xor(s, 2);
    ss += __shfl_xor(ss, 1); ss += __shfl_xor(ss, 2);
    float mean = s * (1.f / 128.f);
    float var = ss * (1.f / 128.f) - mean * mean;
    float rstd = rsqrtf(var + 1e-5f);
    if (grow < NN) {
#pragma unroll
      for (int j = 0; j < 4; ++j) {
        int col = q * 32 + j * 8;
        const float4 g0 = *(const float4*)(lng + col), g1 = *(const float4*)(lng + col + 4);
        const float4 q0 = *(const float4*)(lnb + col), q1 = *(const float4*)(lnb + col + 4);
        float gv[8] = {g0.x, g0.y, g0.z, g0.w, g1.x, g1.y, g1.z, g1.w};
        float bv[8] = {q0.x, q0.y, q0.z, q0.w, q1.x, q1.y, q1.z, q1.w};
        f16x8 o;
#pragma unroll
        for (int e = 0; e < 8; ++e)
          o[e] = (f16)((y[j * 8 + e] - mean) * rstd * gv[e] + bv[e]);
        *(f16x8*)(h16out + (size_t)grow * 128 + col) = o;
      }
    }
  }
}

// ---------------- launch ----------------
extern "C" void kernel_launch(void* const* d_in, const int* in_sizes, int n_in,
                              void* d_out, int out_size, void* d_ws, size_t ws_size,
                              hipStream_t stream) {
  (void)in_sizes; (void)n_in; (void)out_size; (void)ws_size;
  const float* x         = (const float*)d_in[0];
  const float* edge_attr = (const float*)d_in[1];
  const float* h_prev    = (const float*)d_in[2];
  const float* enc_w1    = (const float*)d_in[3];
  const float* enc_b1    = (const float*)d_in[4];
  const float* enc_w2    = (const float*)d_in[5];
  const float* enc_b2    = (const float*)d_in[6];
  const float* et_w1     = (const float*)d_in[7];
  const float* et_b1     = (const float*)d_in[8];
  const float* et_w2     = (const float*)d_in[9];
  const float* et_b2     = (const float*)d_in[10];
  const float* msg_w1    = (const float*)d_in[11];
  const float* msg_b1    = (const float*)d_in[12];
  const float* msg_w2    = (const float*)d_in[13];
  const float* msg_b2    = (const float*)d_in[14];
  const float* upd_w1    = (const float*)d_in[15];
  const float* upd_b1    = (const float*)d_in[16];
  const float* upd_w2    = (const float*)d_in[17];
  const float* upd_b2    = (const float*)d_in[18];
  const float* ln_g      = (const float*)d_in[19];
  const float* ln_b      = (const float*)d_in[20];
  const float* gru_wih   = (const float*)d_in[21];
  const float* gru_whh   = (const float*)d_in[22];
  const float* gru_bih   = (const float*)d_in[23];
  const float* gru_bhh   = (const float*)d_in[24];
  const int* edge_index  = (const int*)d_in[25];
  const int* esrc = edge_index;
  const int* edst = edge_index + NE;

  // workspace layout
  float* ws    = (float*)d_ws;
  float* aggrf = ws;                                 // N*128 f32
  float* wreg  = ws + (size_t)NN * 128;              // 98304 f32 region
  f16*   wg    = (f16*)wreg;                         // 192*512 f16
  float* brz   = wreg + 49152;                       // 256 f32
  f16*   wpenc = (f16*)(brz + 256);                  // 64*512 f16
  f16*   h16a  = (f16*)(wreg + 98304);               // N*128 f16
  f16*   h16b  = h16a + (size_t)NN * 128;            // N*128 f16
  f16*   wpe   = h16b + (size_t)NN * 128;            // 4*136*512 f16 = 278528
  f16*   wpu   = wpe + 4 * 69632;                    // 4*96*512 f16
  f16*   ea16p = wpu + 4 * 96 * 512;                 // E*32 f16 (dst-sorted)
  float* w23f  = (float*)(ea16p + (size_t)NE * 32);  // 4*16384 f32
  float* b23f  = w23f + 4 * 16384;                   // 4*128 f32

  // d_out scratch (consumed before gru writes d_out at the end)
  int* iout   = (int*)d_out;
  int* deg    = iout;                   // NN
  int* offs   = iout + 51200;           // NN+1
  int* cursor = iout + 102400;          // NN
  int* eord   = iout + 153600;          // NE
  int* dstp   = iout + 153600 + NE;     // NE
  int* esp    = iout + 153600 + 2 * NE; // NE
  f16* x16    = (f16*)(iout + 2600000); // N*128 f16

  // ---- CSR build ----
  hipMemsetAsync(deg, 0, NN * sizeof(int), stream);
  hist_kernel<<<(NE + 255) / 256, 256, 0, stream>>>(edst, deg);
  scan_kernel<<<1, 256, 0, stream>>>(deg, offs, NN);
  copy_cursor_kernel<<<(NN + 255) / 256, 256, 0, stream>>>(offs, cursor);
  fill_kernel<<<(NE + 255) / 256, 256, 0, stream>>>(edst, cursor, eord);
  permute_kernel<<<(NE + 255) / 256, 256, 0, stream>>>(eord, esrc, edst, edge_attr,
                                                       dstp, esp, ea16p);

  // ---- W23 fusion + weight packs / input cvt / encoder ----
  w23_kernel<<<32, 256, 0, stream>>>(et_w2, et_b2, msg_w1, msg_b1, w23f, b23f);
  pack_w_kernel<<<(4 * 69632 + 255) / 256, 256, 0, stream>>>(et_w1, w23f, msg_w2, wpe);
  pack_upd_kernel<<<(4 * 96 * 512 + 255) / 256, 256, 0, stream>>>(upd_w1, upd_w2, wpu);
  pack_gru_kernel<<<(192 * 512 + 255) / 256, 256, 0, stream>>>(gru_wih, gru_whh,
                                                               gru_bih, gru_bhh, wg, brz);
  pack_enc_kernel<<<(64 * 512 + 255) / 256, 256, 0, stream>>>(enc_w1, enc_w2, wpenc);
  cvt_x_kernel<<<(NN * 16 + 255) / 256, 256, 0, stream>>>(x, x16);
  encoder_mfma_kernel<<<(NN + 63) / 64, 256, 0, stream>>>(x16, wpenc, enc_b1, enc_b2, h16a);

  f16* hc = h16a;
  f16* hn = h16b;
  for (int l = 0; l < 4; ++l) {
    hipMemsetAsync(aggrf, 0, (size_t)NN * 128 * sizeof(float), stream);
    edge_mfma_kernel<<<NE / 64, 256, 0, stream>>>(
        hc, ea16p, esp, dstp,
        wpe + (size_t)l * 69632,
        et_b1 + l * 128, b23f + l * 128, msg_b2 + l * 128,
        aggrf);
    update_mfma_kernel<<<(NN + 63) / 64, 256, 0, stream>>>(
        hc, aggrf,
        wpu + (size_t)l * 96 * 512,
        upd_b1 + l * 128, upd_b2 + l * 128,
        ln_g, ln_b, hn);
    f16* t = hc; hc = hn; hn = t;
  }
  // after 4 swaps: hc == h16a
  gru_mfma_kernel<<<(NN + 63) / 64, 256, 0, stream>>>(hc, h_prev, wg, brz,
                                                      gru_bih, gru_bhh, (float*)d_out);
}